// Round 16
// baseline (231.420 us; speedup 1.0000x reference)
//
#include <hip/hip_runtime.h>

#define TT 8192
#define CC 512

typedef unsigned short u16;
typedef unsigned int u32;
typedef __attribute__((ext_vector_type(8))) short bf16x8;
typedef __attribute__((ext_vector_type(4))) float f32x4;
typedef __attribute__((ext_vector_type(16))) float f32x16;

#define VMCNT0() asm volatile("s_waitcnt vmcnt(0)" ::: "memory")
#define LGKM0()  asm volatile("s_waitcnt lgkmcnt(0)" ::: "memory")

__device__ __forceinline__ u16 f2bf(float f) {
    u32 u = __float_as_uint(f);
    return (u16)((u + 0x7FFFu + ((u >> 16) & 1u)) >> 16);
}

// pack two f32 -> one u32 of 2 bf16 (round-half-up), lo = a, hi = b
__device__ __forceinline__ u32 pk2bf(float a, float b) {
    return ((__float_as_uint(a) + 0x8000u) >> 16) |
           ((__float_as_uint(b) + 0x8000u) & 0xFFFF0000u);
}

__device__ __forceinline__ void gld16(const u16* g, u16* l) {
    __builtin_amdgcn_global_load_lds(
        (const __attribute__((address_space(1))) u32*)g,
        (__attribute__((address_space(3))) u32*)l, 16, 0, 0);
}

// ---- Kernel 1: LN -> xx (bf16), out = x (residual pre-init), weight transposes ----
__global__ void lnw_kernel(const float* __restrict__ x,
                           const float* __restrict__ scale,
                           const float* __restrict__ bias,
                           const float* __restrict__ Wq,
                           const float* __restrict__ Wk,
                           const float* __restrict__ Wv,
                           u16* __restrict__ xx,
                           u16* __restrict__ wqkt,
                           u16* __restrict__ wvt,
                           float* __restrict__ out) {
    int b = blockIdx.x;
    if (b < 2048) {
        int row = b * 4 + (threadIdx.x >> 6);
        int l = threadIdx.x & 63;
        const float4* xr = (const float4*)(x + (size_t)row * CC);
        float4 a = xr[l * 2], c = xr[l * 2 + 1];
        float4* orow = (float4*)(out + (size_t)row * CC);
        orow[l * 2] = a;
        orow[l * 2 + 1] = c;
        float s = a.x + a.y + a.z + a.w + c.x + c.y + c.z + c.w;
        float q = a.x*a.x + a.y*a.y + a.z*a.z + a.w*a.w
                + c.x*c.x + c.y*c.y + c.z*c.z + c.w*c.w;
        #pragma unroll
        for (int m = 1; m < 64; m <<= 1) {
            s += __shfl_xor(s, m, 64);
            q += __shfl_xor(q, m, 64);
        }
        float mu = s * (1.0f / CC);
        float var = q * (1.0f / CC) - mu * mu;
        float rs = rsqrtf(var + 1e-5f);
        const float4* sc4 = (const float4*)scale;
        const float4* bi4 = (const float4*)bias;
        float4 s1 = sc4[l * 2], s2 = sc4[l * 2 + 1];
        float4 b1 = bi4[l * 2], b2 = bi4[l * 2 + 1];
        bf16x8 o;
        o[0] = (short)f2bf((a.x - mu) * rs * s1.x + b1.x);
        o[1] = (short)f2bf((a.y - mu) * rs * s1.y + b1.y);
        o[2] = (short)f2bf((a.z - mu) * rs * s1.z + b1.z);
        o[3] = (short)f2bf((a.w - mu) * rs * s1.w + b1.w);
        o[4] = (short)f2bf((c.x - mu) * rs * s2.x + b2.x);
        o[5] = (short)f2bf((c.y - mu) * rs * s2.y + b2.y);
        o[6] = (short)f2bf((c.z - mu) * rs * s2.z + b2.z);
        o[7] = (short)f2bf((c.w - mu) * rs * s2.w + b2.w);
        *(bf16x8*)(xx + (size_t)row * CC + l * 8) = o;
    } else {
        int tid = (b - 2048) * 256 + threadIdx.x;   // 0 .. 327679
        if (tid < 65536) {
            int c = tid >> 9, k = tid & 511;
            float w = (c < 64) ? Wq[k * 64 + c] : Wk[k * 64 + (c - 64)];
            wqkt[tid] = f2bf(w);
        } else {
            int i = tid - 65536;
            int c = i >> 9, k = i & 511;
            wvt[i] = f2bf(Wv[k * 512 + c]);
        }
    }
}

// ---------- Kernel 2 (fused): qk = xx @ [Wq|Wk] (blocks 0..127), vT = (xe @ Wv)^T (blocks 128..639) ----------
__global__ __launch_bounds__(256) void qkv_gemm_kernel(const u16* __restrict__ xx,
                                                       const u16* __restrict__ wqkt,
                                                       const float* __restrict__ xe,
                                                       const u16* __restrict__ wvt,
                                                       u16* __restrict__ qk,
                                                       u16* __restrict__ vt) {
    __shared__ u16 tl[128 * 72];
    int w = threadIdx.x >> 6;
    int l = threadIdx.x & 63;
    int l15 = l & 15, g = l >> 4;

    if (blockIdx.x < 128) {
        int r0 = blockIdx.x * 64 + w * 16;
        f32x4 acc[8];
        #pragma unroll
        for (int i = 0; i < 8; ++i) acc[i] = (f32x4){0.f, 0.f, 0.f, 0.f};
        for (int kk = 0; kk < 16; ++kk) {
            int k = kk * 32 + g * 8;
            bf16x8 af = *(const bf16x8*)(xx + (size_t)(r0 + l15) * CC + k);
            #pragma unroll
            for (int Nt = 0; Nt < 8; ++Nt) {
                int c = Nt * 16 + l15;
                bf16x8 bfr = *(const bf16x8*)(wqkt + c * CC + k);
                acc[Nt] = __builtin_amdgcn_mfma_f32_16x16x32_bf16(af, bfr, acc[Nt], 0, 0, 0);
            }
        }
        #pragma unroll
        for (int Nt = 0; Nt < 8; ++Nt) {
            int c = Nt * 16 + l15;
            float scl = (c < 64) ? 0.125f : 1.0f;
            #pragma unroll
            for (int jj = 0; jj < 4; ++jj) {
                int rg = r0 + g * 4 + jj;
                qk[rg * 128 + c] = f2bf(acc[Nt][jj] * scl);
            }
        }
    } else {
        int b2 = blockIdx.x - 128;
        int bm = b2 >> 2, bn = b2 & 3;
        int r0 = bm * 64 + w * 16;
        int c0 = bn * 128;
        f32x4 acc[8];
        #pragma unroll
        for (int i = 0; i < 8; ++i) acc[i] = (f32x4){0.f, 0.f, 0.f, 0.f};
        for (int kk = 0; kk < 16; ++kk) {
            int k = kk * 32 + g * 8;
            const float4* ap = (const float4*)(xe + (size_t)(r0 + l15) * CC + k);
            float4 a1 = ap[0], a2 = ap[1];
            bf16x8 af;
            af[0] = (short)f2bf(a1.x); af[1] = (short)f2bf(a1.y);
            af[2] = (short)f2bf(a1.z); af[3] = (short)f2bf(a1.w);
            af[4] = (short)f2bf(a2.x); af[5] = (short)f2bf(a2.y);
            af[6] = (short)f2bf(a2.z); af[7] = (short)f2bf(a2.w);
            #pragma unroll
            for (int Nt = 0; Nt < 8; ++Nt) {
                int c = c0 + Nt * 16 + l15;
                bf16x8 bfr = *(const bf16x8*)(wvt + c * CC + k);
                acc[Nt] = __builtin_amdgcn_mfma_f32_16x16x32_bf16(af, bfr, acc[Nt], 0, 0, 0);
            }
        }
        #pragma unroll
        for (int Nt = 0; Nt < 8; ++Nt) {
            int c = Nt * 16 + l15;
            #pragma unroll
            for (int jj = 0; jj < 4; ++jj) {
                int r = w * 16 + g * 4 + jj;
                tl[c * 72 + r] = f2bf(acc[Nt][jj]);
            }
        }
        __syncthreads();
        int rb = bm * 64;
        #pragma unroll
        for (int i = 0; i < 4; ++i) {
            int chunk = i * 256 + threadIdx.x;
            int c = chunk >> 3, r8 = chunk & 7;
            bf16x8 o = *(const bf16x8*)&tl[c * 72 + r8 * 8];
            *(bf16x8*)(vt + (size_t)(c0 + c) * TT + rb + r8 * 8) = o;
        }
    }
}

// ---------- Kernel 3: flash, 32x32 MFMA, in-register P (C-pack + shfl_xor exchange) ----------
// Block = [128 q x 64 d], 4 waves (1 q-tile of 32 each), cb=8 col-blocks.
// K read direct from global (L1/L2); S never touches LDS; LDS = V double-buffer only (16KB).
// V_DMA: LDS dest = wave-uniform base + lane*16B (HW contract, m104/m108); swizzle in SOURCE.
__global__ __launch_bounds__(256, 4) void flash_kernel(const u16* __restrict__ qk,
                                                       const u16* __restrict__ vt,
                                                       float* __restrict__ out,
                                                       int CT) {
    extern __shared__ u16 smem[];          // 2 x [64 d][64 s] = 2 x 4096 u16, slot-swizzled

    const int tid = threadIdx.x;
    const int wave = tid >> 6, lane = tid & 63;
    const int l31 = lane & 31, h = lane >> 5;

    // decode blockIdx -> (rt, cb 0..7, ch); big-rt-first
    int b2 = (int)gridDim.x - 1 - (int)blockIdx.x;
    int rt = 0, base = 0;
    for (;;) {
        int nt_ = 2 * rt + 2, nc_ = (nt_ + CT - 1) / CT;
        if (b2 < base + 8 * nc_) break;
        base += 8 * nc_; ++rt;
    }
    const int rem = b2 - base;
    const int cb = rem & 7;
    const int ch = rem >> 3;
    const int nt = 2 * rt + 2, nc = (nt + CT - 1) / CT;
    const int t_lo = ch * nt / nc, t_hi = (ch + 1) * nt / nc;

    // Q B-frags (32x32x16): lane holds Q[q = qrow][a = kt*16 + h*8 + e], pre-scaled by 1/8
    const int qrow = rt * 128 + wave * 32 + l31;
    bf16x8 qf[4];
    #pragma unroll
    for (int k = 0; k < 4; ++k)
        qf[k] = *(const bf16x8*)(qk + (size_t)qrow * 128 + k * 16 + h * 8);

    f32x16 acc0, acc1;                     // d-tiles 0,1 (32 cols each)
    #pragma unroll
    for (int i = 0; i < 16; ++i) { acc0[i] = 0.f; acc1[i] = 0.f; }

    // V DMA: chunk v = (i*4+wave)*64 + lane; d = v>>3 = (i*4+wave)*8 + (lane>>3), sl = lane&7.
    // LDS dest byte = B*8192 + (i*4+wave)*1024 + lane*16  (wave-uniform + lane*16B, compliant).
    // Phys slot sl at row d holds logical s-chunk sl ^ (d&7); d&7 == lane>>3, so
    // source chunk = (lane&7) ^ (lane>>3), applied to the per-lane GLOBAL address.
    #define V_DMA(JT, B) { \
        _Pragma("unroll") \
        for (int i = 0; i < 2; ++i) { \
            int d = (i * 4 + wave) * 8 + (lane >> 3); \
            int cch = (lane & 7) ^ (lane >> 3); \
            gld16(vt + (size_t)(cb * 64 + d) * TT + (JT) * 64 + (cch << 3), \
                  smem + (B) * 4096 + ((i * 4 + wave) * 64 + lane) * 8); \
        } }

    V_DMA(t_lo, 0);

    int cur = 0;
    for (int j = t_lo; j < t_hi; ++j) {
        const bool more = (j + 1 < t_hi);

        VMCNT0();                          // V(j) in LDS (issued a full iter ago)
        LGKM0();
        __builtin_amdgcn_s_barrier();

        if (more) V_DMA(j + 1, cur ^ 1);   // lands during this iteration's compute

        const bool diag = (j >= 2 * rt);
        const u16* Vb = smem + cur * 4096;

        #pragma unroll
        for (int st = 0; st < 2; ++st) {
            // K A-frags for this 32-s tile (4 global loads, L1/L2-resident)
            bf16x8 kf[4];
            int srow = j * 64 + st * 32 + l31;
            #pragma unroll
            for (int k = 0; k < 4; ++k)
                kf[k] = *(const bf16x8*)(qk + (size_t)srow * 128 + 64 + k * 16 + h * 8);

            // swapped QK^T: D[s][q] = sum_a K[s][a] Q[q][a]; lane owns q=l31, s=(r&3)+8(r>>2)+4h
            f32x16 sa;
            #pragma unroll
            for (int i = 0; i < 16; ++i) sa[i] = 0.f;
            #pragma unroll
            for (int k = 0; k < 4; ++k)
                sa = __builtin_amdgcn_mfma_f32_32x32x16_bf16(kf[k], qf[k], sa, 0, 0, 0);

            // causal mask in C/D layout
            if (diag) {
                #pragma unroll
                for (int r = 0; r < 16; ++r) {
                    int sg = j * 64 + st * 32 + (r & 3) + 8 * (r >> 2) + 4 * h;
                    if (sg > qrow) sa[r] = 0.f;
                }
            }

            // pack: c[i] = {bf16(sa[2i]) lo | bf16(sa[2i+1]) hi}
            // h=0 holds s{0,1},{2,3},{8,9},{10,11},{16,17},{18,19},{24,25},{26,27}; h=1 = +4
            u32 c[8];
            #pragma unroll
            for (int i = 0; i < 8; ++i) c[i] = pk2bf(sa[2 * i], sa[2 * i + 1]);

            // exchange halves via shfl_xor(32): A-frag needs lane h to hold s = k2*16 + h*8 + e
            u32 t0 = (u32)__shfl_xor((int)c[0], 32, 64);
            u32 t1 = (u32)__shfl_xor((int)c[1], 32, 64);
            u32 t2 = (u32)__shfl_xor((int)c[2], 32, 64);
            u32 t3 = (u32)__shfl_xor((int)c[3], 32, 64);
            u32 t4 = (u32)__shfl_xor((int)c[4], 32, 64);
            u32 t5 = (u32)__shfl_xor((int)c[5], 32, 64);
            u32 t6 = (u32)__shfl_xor((int)c[6], 32, 64);
            u32 t7 = (u32)__shfl_xor((int)c[7], 32, 64);
            u32 w[8];
            w[0] = h ? t2 : c[0];  w[1] = h ? t3 : c[1];
            w[2] = h ? c[2] : t0;  w[3] = h ? c[3] : t1;
            w[4] = h ? t6 : c[4];  w[5] = h ? t7 : c[5];
            w[6] = h ? c[6] : t4;  w[7] = h ? c[7] : t5;

            // PV: 2 K=16 steps for this st; step kk covers s = kk*16 + h*8 + e
            #pragma unroll
            for (int k2 = 0; k2 < 2; ++k2) {
                union { u32 uw[4]; bf16x8 v; } pu;
                pu.uw[0] = w[k2 * 4 + 0]; pu.uw[1] = w[k2 * 4 + 1];
                pu.uw[2] = w[k2 * 4 + 2]; pu.uw[3] = w[k2 * 4 + 3];
                int kk = st * 2 + k2;
                #pragma unroll
                for (int dt = 0; dt < 2; ++dt) {
                    int d = dt * 32 + l31;
                    int phys = (2 * kk + h) ^ (d & 7);
                    bf16x8 vf = *(const bf16x8*)&Vb[d * 64 + phys * 8];
                    if (dt == 0) acc0 = __builtin_amdgcn_mfma_f32_32x32x16_bf16(pu.v, vf, acc0, 0, 0, 0);
                    else         acc1 = __builtin_amdgcn_mfma_f32_32x32x16_bf16(pu.v, vf, acc1, 0, 0, 0);
                }
            }
        }
        cur ^= 1;
    }

    // epilogue: out pre-initialized to x by lnw; nc==1 -> direct add, else atomic
    float* ob = out + (size_t)(rt * 128) * 512 + cb * 64;
    #pragma unroll
    for (int dt = 0; dt < 2; ++dt) {
        #pragma unroll
        for (int r = 0; r < 16; ++r) {
            int q = wave * 32 + (r & 3) + 8 * (r >> 2) + 4 * h;
            int col = dt * 32 + l31;
            float v = dt ? acc1[r] : acc0[r];
            float* p = &ob[(size_t)q * 512 + col];
            if (nc == 1) *p = *p + v;
            else atomicAdd(p, v);
        }
    }
    #undef V_DMA
}

extern "C" void kernel_launch(void* const* d_in, const int* in_sizes, int n_in,
                              void* d_out, int out_size, void* d_ws, size_t ws_size,
                              hipStream_t stream) {
    (void)in_sizes; (void)n_in; (void)out_size; (void)ws_size;
    const float* x    = (const float*)d_in[0];
    const float* xe   = (const float*)d_in[1];
    const float* lns  = (const float*)d_in[2];
    const float* lnb  = (const float*)d_in[3];
    const float* Wq   = (const float*)d_in[4];
    const float* Wk   = (const float*)d_in[5];
    const float* Wv   = (const float*)d_in[6];
    float* out = (float*)d_out;
    char* ws = (char*)d_ws;

    size_t off_xx   = 0;                                   // bf16 [8192][512]  8 MB
    size_t off_qk   = off_xx   + (size_t)TT * CC * 2;      // bf16 [8192][128]  2 MB
    size_t off_wqkt = off_qk   + (size_t)TT * 128 * 2;     // bf16 [128][512]
    size_t off_wvt  = off_wqkt + (size_t)128 * 512 * 2;    // bf16 [512][512]
    size_t off_vt   = off_wvt  + (size_t)512 * 512 * 2;    // bf16 [512][8192]  8 MB

    // smallest CT with total blocks <= 1024 (4 per CU, all resident)
    int CT = 2, slots = 0;
    for (;;) {
        slots = 0;
        for (int rt = 0; rt < 64; ++rt) slots += 8 * ((2 * rt + 2 + CT - 1) / CT);
        if (slots <= 1024 || CT >= 256) break;
        ++CT;
    }

    u16* xx   = (u16*)(ws + off_xx);
    u16* qk   = (u16*)(ws + off_qk);
    u16* wqkt = (u16*)(ws + off_wqkt);
    u16* wvt  = (u16*)(ws + off_wvt);
    u16* vt   = (u16*)(ws + off_vt);

    const size_t flash_lds = (size_t)(2 * 4096) * sizeof(u16);   // 16 KB

    hipLaunchKernelGGL(lnw_kernel,      dim3(3328), dim3(256), 0, stream,
                       x, lns, lnb, Wq, Wk, Wv, xx, wqkt, wvt, out);
    hipLaunchKernelGGL(qkv_gemm_kernel, dim3(640),  dim3(256), 0, stream,
                       xx, wqkt, xe, wvt, qk, vt);
    hipLaunchKernelGGL(flash_kernel,    dim3(slots), dim3(256), flash_lds, stream,
                       qk, vt, out, CT);
}

// Round 17
// 138.601 us; speedup vs baseline: 1.6697x; 1.6697x over previous
//
#include <hip/hip_runtime.h>

#define TT 8192
#define CC 512

typedef unsigned short u16;
typedef unsigned int u32;
typedef __attribute__((ext_vector_type(8))) short bf16x8;
typedef __attribute__((ext_vector_type(4))) float f32x4;

#define VMCNT0() asm volatile("s_waitcnt vmcnt(0)" ::: "memory")
#define LGKM0()  asm volatile("s_waitcnt lgkmcnt(0)" ::: "memory")

__device__ __forceinline__ u16 f2bf(float f) {          // RNE (cold paths)
    u32 u = __float_as_uint(f);
    return (u16)((u + 0x7FFFu + ((u >> 16) & 1u)) >> 16);
}
__device__ __forceinline__ u16 f2bf_fast(float f) {     // round-half-up (hot path)
    return (u16)((__float_as_uint(f) + 0x8000u) >> 16);
}

__device__ __forceinline__ void gld16(const u16* g, u16* l) {
    __builtin_amdgcn_global_load_lds(
        (const __attribute__((address_space(1))) u32*)g,
        (__attribute__((address_space(3))) u32*)l, 16, 0, 0);
}

// ---- Kernel 1: LN -> xx (bf16), out = x (residual pre-init), wtrans, xe -> xeb (bf16) ----
__global__ void lnw_kernel(const float* __restrict__ x,
                           const float* __restrict__ scale,
                           const float* __restrict__ bias,
                           const float* __restrict__ Wq,
                           const float* __restrict__ Wk,
                           const float* __restrict__ Wv,
                           const float* __restrict__ xe,
                           u16* __restrict__ xx,
                           u16* __restrict__ wqkt,
                           u16* __restrict__ wvt,
                           u16* __restrict__ xeb,
                           float* __restrict__ out) {
    int b = blockIdx.x;
    if (b < 2048) {
        int row = b * 4 + (threadIdx.x >> 6);
        int l = threadIdx.x & 63;
        const float4* xr = (const float4*)(x + (size_t)row * CC);
        float4 a = xr[l * 2], c = xr[l * 2 + 1];
        float4* orow = (float4*)(out + (size_t)row * CC);
        orow[l * 2] = a;
        orow[l * 2 + 1] = c;
        float s = a.x + a.y + a.z + a.w + c.x + c.y + c.z + c.w;
        float q = a.x*a.x + a.y*a.y + a.z*a.z + a.w*a.w
                + c.x*c.x + c.y*c.y + c.z*c.z + c.w*c.w;
        #pragma unroll
        for (int m = 1; m < 64; m <<= 1) {
            s += __shfl_xor(s, m, 64);
            q += __shfl_xor(q, m, 64);
        }
        float mu = s * (1.0f / CC);
        float var = q * (1.0f / CC) - mu * mu;
        float rs = rsqrtf(var + 1e-5f);
        const float4* sc4 = (const float4*)scale;
        const float4* bi4 = (const float4*)bias;
        float4 s1 = sc4[l * 2], s2 = sc4[l * 2 + 1];
        float4 b1 = bi4[l * 2], b2 = bi4[l * 2 + 1];
        bf16x8 o;
        o[0] = (short)f2bf((a.x - mu) * rs * s1.x + b1.x);
        o[1] = (short)f2bf((a.y - mu) * rs * s1.y + b1.y);
        o[2] = (short)f2bf((a.z - mu) * rs * s1.z + b1.z);
        o[3] = (short)f2bf((a.w - mu) * rs * s1.w + b1.w);
        o[4] = (short)f2bf((c.x - mu) * rs * s2.x + b2.x);
        o[5] = (short)f2bf((c.y - mu) * rs * s2.y + b2.y);
        o[6] = (short)f2bf((c.z - mu) * rs * s2.z + b2.z);
        o[7] = (short)f2bf((c.w - mu) * rs * s2.w + b2.w);
        *(bf16x8*)(xx + (size_t)row * CC + l * 8) = o;
    } else if (b < 3328) {
        int tid = (b - 2048) * 256 + threadIdx.x;   // 0 .. 327679
        if (tid < 65536) {
            int c = tid >> 9, k = tid & 511;
            float w = (c < 64) ? Wq[k * 64 + c] : Wk[k * 64 + (c - 64)];
            wqkt[tid] = f2bf(w);
        } else {
            int i = tid - 65536;
            int c = i >> 9, k = i & 511;
            wvt[i] = f2bf(Wv[k * 512 + c]);
        }
    } else {
        size_t i = (size_t)(b - 3328) * 2048 + (size_t)threadIdx.x * 8;
        float4 a = *(const float4*)(xe + i);
        float4 c = *(const float4*)(xe + i + 4);
        bf16x8 o;
        o[0] = (short)f2bf(a.x); o[1] = (short)f2bf(a.y);
        o[2] = (short)f2bf(a.z); o[3] = (short)f2bf(a.w);
        o[4] = (short)f2bf(c.x); o[5] = (short)f2bf(c.y);
        o[6] = (short)f2bf(c.z); o[7] = (short)f2bf(c.w);
        *(bf16x8*)(xeb + i) = o;
    }
}

// ---- Kernel 2 (fused): qk = xx @ [Wq|Wk] (blocks 0..255), vT = (xeb @ Wv)^T (blocks 256..767) ----
__global__ __launch_bounds__(256) void qkv_gemm_kernel(const u16* __restrict__ xx,
                                                       const u16* __restrict__ wqkt,
                                                       const u16* __restrict__ xeb,
                                                       const u16* __restrict__ wvt,
                                                       u16* __restrict__ qk,
                                                       u16* __restrict__ vt) {
    __shared__ u16 tl[128 * 72];
    int w = threadIdx.x >> 6;
    int l = threadIdx.x & 63;
    int l15 = l & 15, g = l >> 4;

    if (blockIdx.x < 256) {
        // qk part: 32 rows/block; wave w: rows (w&1)*16, col quadrant (w>>1)*4 Nt
        int r0 = blockIdx.x * 32 + (w & 1) * 16;
        int n0 = (w >> 1) * 4;
        f32x4 acc[4];
        #pragma unroll
        for (int i = 0; i < 4; ++i) acc[i] = (f32x4){0.f, 0.f, 0.f, 0.f};
        for (int kk = 0; kk < 16; ++kk) {
            int k = kk * 32 + g * 8;
            bf16x8 af = *(const bf16x8*)(xx + (size_t)(r0 + l15) * CC + k);
            #pragma unroll
            for (int Nt = 0; Nt < 4; ++Nt) {
                int c = (n0 + Nt) * 16 + l15;
                bf16x8 bfr = *(const bf16x8*)(wqkt + c * CC + k);
                acc[Nt] = __builtin_amdgcn_mfma_f32_16x16x32_bf16(af, bfr, acc[Nt], 0, 0, 0);
            }
        }
        #pragma unroll
        for (int Nt = 0; Nt < 4; ++Nt) {
            int c = (n0 + Nt) * 16 + l15;
            float scl = (c < 64) ? 0.125f : 1.0f;
            #pragma unroll
            for (int jj = 0; jj < 4; ++jj) {
                int rg = r0 + g * 4 + jj;
                qk[rg * 128 + c] = f2bf(acc[Nt][jj] * scl);
            }
        }
    } else {
        // v part: 64 rows x 128 cols per block; bf16 input
        int b2 = blockIdx.x - 256;
        int bm = b2 >> 2, bn = b2 & 3;
        int r0 = bm * 64 + w * 16;
        int c0 = bn * 128;
        f32x4 acc[8];
        #pragma unroll
        for (int i = 0; i < 8; ++i) acc[i] = (f32x4){0.f, 0.f, 0.f, 0.f};
        for (int kk = 0; kk < 16; ++kk) {
            int k = kk * 32 + g * 8;
            bf16x8 af = *(const bf16x8*)(xeb + (size_t)(r0 + l15) * CC + k);
            #pragma unroll
            for (int Nt = 0; Nt < 8; ++Nt) {
                int c = c0 + Nt * 16 + l15;
                bf16x8 bfr = *(const bf16x8*)(wvt + c * CC + k);
                acc[Nt] = __builtin_amdgcn_mfma_f32_16x16x32_bf16(af, bfr, acc[Nt], 0, 0, 0);
            }
        }
        #pragma unroll
        for (int Nt = 0; Nt < 8; ++Nt) {
            int c = Nt * 16 + l15;
            #pragma unroll
            for (int jj = 0; jj < 4; ++jj) {
                int r = w * 16 + g * 4 + jj;
                tl[c * 72 + r] = f2bf(acc[Nt][jj]);
            }
        }
        __syncthreads();
        int rb = bm * 64;
        #pragma unroll
        for (int i = 0; i < 4; ++i) {
            int chunk = i * 256 + threadIdx.x;
            int c = chunk >> 3, r8 = chunk & 7;
            bf16x8 o = *(const bf16x8*)&tl[c * 72 + r8 * 8];
            *(bf16x8*)(vt + (size_t)(c0 + c) * TT + rb + r8 * 8) = o;
        }
    }
}

// ---------- Kernel 3: flash, BM=128 x BN=128, 8 waves, 64KB LDS (2 blocks/CU) ----------
// K/V DMA double-buffered (global_load_lds, issue-after-barrier, full-iter span);
// j-loop unrolled x2 (static buffer parity); mask only on diagonal visits.  [r11 verbatim]
__global__ __launch_bounds__(512, 4) void flash_kernel(const u16* __restrict__ qk,
                                                       const u16* __restrict__ vt,
                                                       float* __restrict__ out,
                                                       int CT) {
    extern __shared__ u16 smem[];
    u16* const Klds = smem;            // 2 x [64 s][64 a] swizzled, 16KB
    u16* const Slds = smem + 8192;     // [128 r][64 s] swizzled, 16KB
    u16* const Vlds = smem + 16384;    // 2 x [128 c][64 s] swizzled, 32KB

    const int tid = threadIdx.x;
    const int w = tid >> 6, l = tid & 63;
    const int l15 = l & 15, g = l >> 4;
    const int wr = w >> 2, wcol = w & 3;     // PV: rows wr*64, cols wcol*32

    // decode blockIdx -> (rt, cb 0..3, ch); big-rt-first
    int b2 = (int)gridDim.x - 1 - (int)blockIdx.x;
    int rt = 0, base = 0;
    for (;;) {
        int nt_ = 2 * rt + 2, nc_ = (nt_ + CT - 1) / CT;
        if (b2 < base + 4 * nc_) break;
        base += 4 * nc_; ++rt;
    }
    const int rem = b2 - base;
    const int cb = rem & 3;
    const int ch = rem >> 2;
    const int nt = 2 * rt + 2, nc = (nt + CT - 1) / CT;
    const int t_lo = ch * nt / nc, t_hi = (ch + 1) * nt / nc;

    // Q fragments: wave w owns S rows [w*16, +16), pre-scaled by 1/8
    const int qrow = rt * 128 + w * 16 + l15;
    const bf16x8 qs0 = *(const bf16x8*)(qk + (size_t)qrow * 128 + g * 8);
    const bf16x8 qs1 = *(const bf16x8*)(qk + (size_t)qrow * 128 + 32 + g * 8);

    f32x4 acc[4][2];
    #pragma unroll
    for (int m = 0; m < 4; ++m)
        #pragma unroll
        for (int n = 0; n < 2; ++n) acc[m][n] = (f32x4){0.f, 0.f, 0.f, 0.f};

    // K DMA: 1 gld16/thread, linear dst, pre-swizzled source
    const int sIk = tid >> 3, pk = tid & 7;
    const int ka8 = (pk ^ (sIk & 7)) << 3;
    // V DMA: 2 gld16/thread
    const int vr = w * 8 + (l >> 3);
    const int vsw = ((l & 7) ^ (l >> 3)) << 3;

    #define K_DMA(JT, B) gld16(qk + (size_t)((JT) * 64 + sIk) * 128 + 64 + ka8, \
                               Klds + (B) * 4096 + sIk * 64 + pk * 8)
    #define V_DMA(JT, B) { \
        _Pragma("unroll") \
        for (int i = 0; i < 2; ++i) { \
            int c = i * 64 + vr; \
            gld16(vt + (size_t)(cb * 128 + c) * TT + (JT) * 64 + vsw, \
                  Vlds + (B) * 8192 + c * 64 + (l & 7) * 8); \
        } }

    // one flash iteration; CUR is a literal so all LDS addressing is static
    #define FLASH_ITER(J, CUR, MORE) { \
        VMCNT0(); \
        LGKM0(); \
        __builtin_amdgcn_s_barrier(); \
        if (MORE) { V_DMA((J) + 1, (CUR) ^ 1); K_DMA((J) + 1, (CUR) ^ 1); } \
        const u16* Kb = Klds + (CUR) * 4096; \
        f32x4 sacc[4]; \
        _Pragma("unroll") \
        for (int Nt = 0; Nt < 4; ++Nt) sacc[Nt] = (f32x4){0.f, 0.f, 0.f, 0.f}; \
        __builtin_amdgcn_s_setprio(1); \
        _Pragma("unroll") \
        for (int Nt = 0; Nt < 4; ++Nt) { \
            int srow = Nt * 16 + l15; \
            _Pragma("unroll") \
            for (int ka = 0; ka < 2; ++ka) { \
                int sl = (ka * 4 + g) ^ (srow & 7); \
                bf16x8 kf = *(const bf16x8*)&Kb[srow * 64 + sl * 8]; \
                sacc[Nt] = __builtin_amdgcn_mfma_f32_16x16x32_bf16( \
                    ka ? qs1 : qs0, kf, sacc[Nt], 0, 0, 0); \
            } \
        } \
        __builtin_amdgcn_s_setprio(0); \
        if ((J) >= 2 * rt) { \
            _Pragma("unroll") \
            for (int Nt = 0; Nt < 4; ++Nt) { \
                int scol = Nt * 16 + l15; \
                _Pragma("unroll") \
                for (int jj = 0; jj < 4; ++jj) { \
                    int row = w * 16 + g * 4 + jj; \
                    float val = sacc[Nt][jj]; \
                    if (((J) * 64 + scol) > rt * 128 + row) val = 0.f; \
                    Slds[row * 64 + ((((scol >> 3) ^ (row & 7)) << 3) + (scol & 7))] = f2bf_fast(val); \
                } \
            } \
        } else { \
            _Pragma("unroll") \
            for (int Nt = 0; Nt < 4; ++Nt) { \
                int scol = Nt * 16 + l15; \
                _Pragma("unroll") \
                for (int jj = 0; jj < 4; ++jj) { \
                    int row = w * 16 + g * 4 + jj; \
                    Slds[row * 64 + ((((scol >> 3) ^ (row & 7)) << 3) + (scol & 7))] = f2bf_fast(sacc[Nt][jj]); \
                } \
            } \
        } \
        LGKM0(); \
        __builtin_amdgcn_s_barrier(); \
        const u16* Vb = Vlds + (CUR) * 8192; \
        __builtin_amdgcn_s_setprio(1); \
        _Pragma("unroll") \
        for (int ka = 0; ka < 2; ++ka) { \
            bf16x8 sf[4], vf[2]; \
            _Pragma("unroll") \
            for (int Mt = 0; Mt < 4; ++Mt) { \
                int row = wr * 64 + Mt * 16 + l15; \
                int sl = (ka * 4 + g) ^ (row & 7); \
                sf[Mt] = *(const bf16x8*)&Slds[row * 64 + sl * 8]; \
            } \
            _Pragma("unroll") \
            for (int Nt = 0; Nt < 2; ++Nt) { \
                int cv = wcol * 32 + Nt * 16 + l15; \
                int ph = (ka * 4 + g) ^ (cv & 7); \
                vf[Nt] = *(const bf16x8*)&Vb[cv * 64 + ph * 8]; \
            } \
            _Pragma("unroll") \
            for (int Nt = 0; Nt < 2; ++Nt) \
                _Pragma("unroll") \
                for (int Mt = 0; Mt < 4; ++Mt) \
                    acc[Mt][Nt] = __builtin_amdgcn_mfma_f32_16x16x32_bf16( \
                        sf[Mt], vf[Nt], acc[Mt][Nt], 0, 0, 0); \
        } \
        __builtin_amdgcn_s_setprio(0); \
    }

    // prologue: DMA(t_lo) -> buf0
    V_DMA(t_lo, 0);
    K_DMA(t_lo, 0);

    // unrolled x2 main loop (static buffer parity), tail handles odd chunk length
    int j = t_lo;
    for (; j + 1 < t_hi; j += 2) {
        FLASH_ITER(j, 0, true);
        FLASH_ITER(j + 1, 1, (j + 2 < t_hi));
    }
    if (j < t_hi) FLASH_ITER(j, 0, false);

    // epilogue: nc==1 -> plain load+add+store (out pre-initialized to x); else atomic
    float* ob = out + (size_t)(rt * 128) * 512 + cb * 128;
    if (nc == 1) {
        #pragma unroll
        for (int Mt = 0; Mt < 4; ++Mt) {
            #pragma unroll
            for (int Nt = 0; Nt < 2; ++Nt) {
                int col = wcol * 32 + Nt * 16 + l15;
                #pragma unroll
                for (int jj = 0; jj < 4; ++jj) {
                    int row = wr * 64 + Mt * 16 + g * 4 + jj;
                    float* p = &ob[(size_t)row * 512 + col];
                    *p = *p + acc[Mt][Nt][jj];
                }
            }
        }
    } else {
        #pragma unroll
        for (int Mt = 0; Mt < 4; ++Mt) {
            #pragma unroll
            for (int Nt = 0; Nt < 2; ++Nt) {
                int col = wcol * 32 + Nt * 16 + l15;
                #pragma unroll
                for (int jj = 0; jj < 4; ++jj) {
                    int row = wr * 64 + Mt * 16 + g * 4 + jj;
                    atomicAdd(&ob[(size_t)row * 512 + col], acc[Mt][Nt][jj]);
                }
            }
        }
    }
    #undef K_DMA
    #undef V_DMA
    #undef FLASH_ITER
}

extern "C" void kernel_launch(void* const* d_in, const int* in_sizes, int n_in,
                              void* d_out, int out_size, void* d_ws, size_t ws_size,
                              hipStream_t stream) {
    (void)in_sizes; (void)n_in; (void)out_size; (void)ws_size;
    const float* x    = (const float*)d_in[0];
    const float* xe   = (const float*)d_in[1];
    const float* lns  = (const float*)d_in[2];
    const float* lnb  = (const float*)d_in[3];
    const float* Wq   = (const float*)d_in[4];
    const float* Wk   = (const float*)d_in[5];
    const float* Wv   = (const float*)d_in[6];
    float* out = (float*)d_out;
    char* ws = (char*)d_ws;

    size_t off_xx   = 0;                                   // bf16 [8192][512]  8 MB
    size_t off_qk   = off_xx   + (size_t)TT * CC * 2;      // bf16 [8192][128]  2 MB
    size_t off_wqkt = off_qk   + (size_t)TT * 128 * 2;     // bf16 [128][512]
    size_t off_wvt  = off_wqkt + (size_t)128 * 512 * 2;    // bf16 [512][512]
    size_t off_vt   = off_wvt  + (size_t)512 * 512 * 2;    // bf16 [512][8192]  8 MB
    size_t off_xeb  = off_vt   + (size_t)TT * CC * 2;      // bf16 [8192][512]  8 MB

    // smallest CT with total blocks <= 512 (2 per CU, all resident)
    int CT = 2, slots = 0;
    for (;;) {
        slots = 0;
        for (int rt = 0; rt < 64; ++rt) slots += 4 * ((2 * rt + 2 + CT - 1) / CT);
        if (slots <= 512 || CT >= 256) break;
        ++CT;
    }

    u16* xx   = (u16*)(ws + off_xx);
    u16* qk   = (u16*)(ws + off_qk);
    u16* wqkt = (u16*)(ws + off_wqkt);
    u16* wvt  = (u16*)(ws + off_wvt);
    u16* vt   = (u16*)(ws + off_vt);
    u16* xeb  = (u16*)(ws + off_xeb);

    const size_t flash_lds = (size_t)(8192 + 8192 + 16384) * sizeof(u16);  // 64 KB

    hipLaunchKernelGGL(lnw_kernel,      dim3(5376), dim3(256), 0, stream,
                       x, lns, lnb, Wq, Wk, Wv, xe, xx, wqkt, wvt, xeb, out);
    hipLaunchKernelGGL(qkv_gemm_kernel, dim3(768),  dim3(256), 0, stream,
                       xx, wqkt, xeb, wvt, qk, vt);
    hipLaunchKernelGGL(flash_kernel,    dim3(slots), dim3(512), flash_lds, stream,
                       qk, vt, out, CT);
}

// Round 18
// 97.625 us; speedup vs baseline: 2.3705x; 1.4197x over previous
//
#include <hip/hip_runtime.h>

#define TT 8192
#define CC 512

typedef unsigned short u16;
typedef unsigned int u32;
typedef __attribute__((ext_vector_type(8))) short bf16x8;
typedef __attribute__((ext_vector_type(4))) float f32x4;

__device__ __forceinline__ u16 f2bf(float f) {
    u32 u = __float_as_uint(f);
    return (u16)((u + 0x7FFFu + ((u >> 16) & 1u)) >> 16);
}

// ---- Kernel 1: LN -> xx (bf16), weight transposes, xe -> xeb (bf16) ----
__global__ void lnw_kernel(const float* __restrict__ x,
                           const float* __restrict__ scale,
                           const float* __restrict__ bias,
                           const float* __restrict__ Wq,
                           const float* __restrict__ Wk,
                           const float* __restrict__ Wv,
                           const float* __restrict__ xe,
                           u16* __restrict__ xx,
                           u16* __restrict__ wqkt,
                           u16* __restrict__ wvt,
                           u16* __restrict__ xeb) {
    int b = blockIdx.x;
    if (b < 2048) {
        int row = b * 4 + (threadIdx.x >> 6);
        int l = threadIdx.x & 63;
        const float4* xr = (const float4*)(x + (size_t)row * CC);
        float4 a = xr[l * 2], c = xr[l * 2 + 1];
        float s = a.x + a.y + a.z + a.w + c.x + c.y + c.z + c.w;
        float q = a.x*a.x + a.y*a.y + a.z*a.z + a.w*a.w
                + c.x*c.x + c.y*c.y + c.z*c.z + c.w*c.w;
        #pragma unroll
        for (int m = 1; m < 64; m <<= 1) {
            s += __shfl_xor(s, m, 64);
            q += __shfl_xor(q, m, 64);
        }
        float mu = s * (1.0f / CC);
        float var = q * (1.0f / CC) - mu * mu;
        float rs = rsqrtf(var + 1e-5f);
        const float4* sc4 = (const float4*)scale;
        const float4* bi4 = (const float4*)bias;
        float4 s1 = sc4[l * 2], s2 = sc4[l * 2 + 1];
        float4 b1 = bi4[l * 2], b2 = bi4[l * 2 + 1];
        bf16x8 o;
        o[0] = (short)f2bf((a.x - mu) * rs * s1.x + b1.x);
        o[1] = (short)f2bf((a.y - mu) * rs * s1.y + b1.y);
        o[2] = (short)f2bf((a.z - mu) * rs * s1.z + b1.z);
        o[3] = (short)f2bf((a.w - mu) * rs * s1.w + b1.w);
        o[4] = (short)f2bf((c.x - mu) * rs * s2.x + b2.x);
        o[5] = (short)f2bf((c.y - mu) * rs * s2.y + b2.y);
        o[6] = (short)f2bf((c.z - mu) * rs * s2.z + b2.z);
        o[7] = (short)f2bf((c.w - mu) * rs * s2.w + b2.w);
        *(bf16x8*)(xx + (size_t)row * CC + l * 8) = o;
    } else if (b < 3328) {
        int tid = (b - 2048) * 256 + threadIdx.x;   // 0 .. 327679
        if (tid < 65536) {
            int c = tid >> 9, k = tid & 511;
            float w = (c < 64) ? Wq[k * 64 + c] : Wk[k * 64 + (c - 64)];
            wqkt[tid] = f2bf(w);
        } else {
            int i = tid - 65536;
            int c = i >> 9, k = i & 511;
            wvt[i] = f2bf(Wv[k * 512 + c]);
        }
    } else {
        size_t i = (size_t)(b - 3328) * 2048 + (size_t)threadIdx.x * 8;
        float4 a = *(const float4*)(xe + i);
        float4 c = *(const float4*)(xe + i + 4);
        bf16x8 o;
        o[0] = (short)f2bf(a.x); o[1] = (short)f2bf(a.y);
        o[2] = (short)f2bf(a.z); o[3] = (short)f2bf(a.w);
        o[4] = (short)f2bf(c.x); o[5] = (short)f2bf(c.y);
        o[6] = (short)f2bf(c.z); o[7] = (short)f2bf(c.w);
        *(bf16x8*)(xeb + i) = o;
    }
}

// ---- Kernel 2 (fused): qk = xx @ [Wq|Wk] + kt (blocks 0..255), vT = (xeb @ Wv)^T (blocks 256..767) ----
__global__ __launch_bounds__(256) void qkv_gemm_kernel(const u16* __restrict__ xx,
                                                       const u16* __restrict__ wqkt,
                                                       const u16* __restrict__ xeb,
                                                       const u16* __restrict__ wvt,
                                                       u16* __restrict__ qk,
                                                       u16* __restrict__ kt,
                                                       u16* __restrict__ vt) {
    __shared__ u16 tl[128 * 72];
    int w = threadIdx.x >> 6;
    int l = threadIdx.x & 63;
    int l15 = l & 15, g = l >> 4;

    if (blockIdx.x < 256) {
        // qk part: 32 rows/block; wave w: rows (w&1)*16, col quadrant n0=(w>>1)*4
        int r0b = blockIdx.x * 32;
        int r0 = r0b + (w & 1) * 16;
        int n0 = (w >> 1) * 4;
        f32x4 acc[4];
        #pragma unroll
        for (int i = 0; i < 4; ++i) acc[i] = (f32x4){0.f, 0.f, 0.f, 0.f};
        for (int kk = 0; kk < 16; ++kk) {
            int k = kk * 32 + g * 8;
            bf16x8 af = *(const bf16x8*)(xx + (size_t)(r0 + l15) * CC + k);
            #pragma unroll
            for (int Nt = 0; Nt < 4; ++Nt) {
                int c = (n0 + Nt) * 16 + l15;
                bf16x8 bfr = *(const bf16x8*)(wqkt + c * CC + k);
                acc[Nt] = __builtin_amdgcn_mfma_f32_16x16x32_bf16(af, bfr, acc[Nt], 0, 0, 0);
            }
        }
        #pragma unroll
        for (int Nt = 0; Nt < 4; ++Nt) {
            int c = (n0 + Nt) * 16 + l15;
            float scl = (c < 64) ? 0.125f : 1.0f;
            #pragma unroll
            for (int jj = 0; jj < 4; ++jj) {
                int rg = r0 + g * 4 + jj;
                qk[rg * 128 + c] = f2bf(acc[Nt][jj] * scl);
            }
        }
        // kt: waves with n0==4 hold k (a = c-64); transpose via LDS (stride 40 u16 -> 16B-aligned rows)
        if (n0 == 4) {
            #pragma unroll
            for (int Nt = 0; Nt < 4; ++Nt) {
                int a = Nt * 16 + l15;
                #pragma unroll
                for (int jj = 0; jj < 4; ++jj) {
                    int r = (w & 1) * 16 + g * 4 + jj;   // 0..31
                    tl[a * 40 + r] = f2bf(acc[Nt][jj]);
                }
            }
        }
        __syncthreads();
        int a = threadIdx.x >> 2, r8 = threadIdx.x & 3;
        bf16x8 o = *(const bf16x8*)&tl[a * 40 + r8 * 8];
        *(bf16x8*)(kt + (size_t)a * TT + r0b + r8 * 8) = o;
    } else {
        // v part: 64 rows x 128 cols per block; bf16 input
        int b2 = blockIdx.x - 256;
        int bm = b2 >> 2, bn = b2 & 3;
        int r0 = bm * 64 + w * 16;
        int c0 = bn * 128;
        f32x4 acc[8];
        #pragma unroll
        for (int i = 0; i < 8; ++i) acc[i] = (f32x4){0.f, 0.f, 0.f, 0.f};
        for (int kk = 0; kk < 16; ++kk) {
            int k = kk * 32 + g * 8;
            bf16x8 af = *(const bf16x8*)(xeb + (size_t)(r0 + l15) * CC + k);
            #pragma unroll
            for (int Nt = 0; Nt < 8; ++Nt) {
                int c = c0 + Nt * 16 + l15;
                bf16x8 bfr = *(const bf16x8*)(wvt + c * CC + k);
                acc[Nt] = __builtin_amdgcn_mfma_f32_16x16x32_bf16(af, bfr, acc[Nt], 0, 0, 0);
            }
        }
        #pragma unroll
        for (int Nt = 0; Nt < 8; ++Nt) {
            int c = Nt * 16 + l15;
            #pragma unroll
            for (int jj = 0; jj < 4; ++jj) {
                int r = w * 16 + g * 4 + jj;
                tl[c * 72 + r] = f2bf(acc[Nt][jj]);
            }
        }
        __syncthreads();
        int rb = bm * 64;
        #pragma unroll
        for (int i = 0; i < 4; ++i) {
            int chunk = i * 256 + threadIdx.x;
            int c = chunk >> 3, r8 = chunk & 7;
            bf16x8 o = *(const bf16x8*)&tl[c * 72 + r8 * 8];
            *(bf16x8*)(vt + (size_t)(c0 + c) * TT + rb + r8 * 8) = o;
        }
    }
}

// ---- Kernel 3: Gt[j][c][a] = sum_{s in tile j} V[s][c] K[s][a]  (f32), j = 0..127 ----
__global__ __launch_bounds__(512) void gkv_kernel(const u16* __restrict__ vt,
                                                  const u16* __restrict__ kt,
                                                  float* __restrict__ Gt) {
    int j = blockIdx.x;
    int w = threadIdx.x >> 6, l = threadIdx.x & 63;
    int l15 = l & 15, g = l >> 4;
    int c0 = w * 64;

    f32x4 acc[4][4];
    #pragma unroll
    for (int m = 0; m < 4; ++m)
        #pragma unroll
        for (int n = 0; n < 4; ++n) acc[m][n] = (f32x4){0.f, 0.f, 0.f, 0.f};

    #pragma unroll
    for (int ka = 0; ka < 2; ++ka) {
        int k = j * 64 + ka * 32 + g * 8;
        bf16x8 af[4], bfr[4];
        #pragma unroll
        for (int Mt = 0; Mt < 4; ++Mt)
            af[Mt] = *(const bf16x8*)(vt + (size_t)(c0 + Mt * 16 + l15) * TT + k);
        #pragma unroll
        for (int Nt = 0; Nt < 4; ++Nt)
            bfr[Nt] = *(const bf16x8*)(kt + (size_t)(Nt * 16 + l15) * TT + k);
        #pragma unroll
        for (int Mt = 0; Mt < 4; ++Mt)
            #pragma unroll
            for (int Nt = 0; Nt < 4; ++Nt)
                acc[Mt][Nt] = __builtin_amdgcn_mfma_f32_16x16x32_bf16(af[Mt], bfr[Nt], acc[Mt][Nt], 0, 0, 0);
    }

    float* gp = Gt + (size_t)j * 32768;
    #pragma unroll
    for (int Mt = 0; Mt < 4; ++Mt) {
        #pragma unroll
        for (int Nt = 0; Nt < 4; ++Nt) {
            int a = Nt * 16 + l15;
            #pragma unroll
            for (int jj = 0; jj < 4; ++jj) {
                int c = c0 + Mt * 16 + g * 4 + jj;
                gp[c * 64 + a] = acc[Mt][Nt][jj];
            }
        }
    }
}

// ---- Kernel 4: scan -> ptb[i][c][a] = bf16( sum_{j < 2i} Gt[j][c][a] ), i = 0..63 ----
__global__ __launch_bounds__(256) void scan_kernel(const float* __restrict__ Gt,
                                                   u16* __restrict__ ptb) {
    int e = blockIdx.x * 256 + threadIdx.x;   // 0..32767
    float acc = 0.f;
    ptb[e] = 0;
    for (int i = 1; i < 64; ++i) {
        acc += Gt[(size_t)(2 * i - 2) * 32768 + e] + Gt[(size_t)(2 * i - 1) * 32768 + e];
        ptb[(size_t)i * 32768 + e] = f2bf(acc);
    }
}

// ---- Kernel 5: out = x + Q_i @ P_i + tril(Q_i K_diag^T) @ V_diag ; single-shot, 1 barrier ----
__global__ __launch_bounds__(512) void out_kernel(const u16* __restrict__ qk,
                                                  const u16* __restrict__ ptb,
                                                  const u16* __restrict__ vt,
                                                  const float* __restrict__ x,
                                                  float* __restrict__ out) {
    __shared__ u16 Slds[128 * 128];   // [r][128 s], 16-slot XOR swizzle, 32KB

    const int tid = threadIdx.x;
    const int w = tid >> 6, l = tid & 63;
    const int l15 = l & 15, g = l >> 4;
    const int wr = w >> 2, wcol = w & 3;

    const int rt = (int)blockIdx.x >> 2;
    const int cb = (int)blockIdx.x & 3;

    f32x4 acc[4][2];
    #pragma unroll
    for (int m = 0; m < 4; ++m)
        #pragma unroll
        for (int n = 0; n < 2; ++n) acc[m][n] = (f32x4){0.f, 0.f, 0.f, 0.f};

    // ---- diag QK^T: wave w computes S rows [w*16, +16) x 128 s ----
    const int dq = rt * 128 + w * 16 + l15;
    const bf16x8 qa0 = *(const bf16x8*)(qk + (size_t)dq * 128 + g * 8);
    const bf16x8 qa1 = *(const bf16x8*)(qk + (size_t)dq * 128 + 32 + g * 8);
    #pragma unroll
    for (int Nt = 0; Nt < 8; ++Nt) {
        int scol = Nt * 16 + l15;
        f32x4 sacc = (f32x4){0.f, 0.f, 0.f, 0.f};
        #pragma unroll
        for (int ka = 0; ka < 2; ++ka) {
            bf16x8 kf = *(const bf16x8*)(qk + (size_t)(rt * 128 + scol) * 128 + 64 + ka * 32 + g * 8);
            sacc = __builtin_amdgcn_mfma_f32_16x16x32_bf16(ka ? qa1 : qa0, kf, sacc, 0, 0, 0);
        }
        #pragma unroll
        for (int jj = 0; jj < 4; ++jj) {
            int row = w * 16 + g * 4 + jj;
            float val = (scol > row) ? 0.f : sacc[jj];
            int slot = (scol >> 3) ^ (row & 15);
            Slds[row * 128 + slot * 8 + (scol & 7)] = f2bf(val);
        }
    }

    // ---- main: acc += Q_i @ P_i (K=64) ----
    #pragma unroll
    for (int ka = 0; ka < 2; ++ka) {
        bf16x8 qf[4], pf[2];
        #pragma unroll
        for (int Mt = 0; Mt < 4; ++Mt)
            qf[Mt] = *(const bf16x8*)(qk + (size_t)(rt * 128 + wr * 64 + Mt * 16 + l15) * 128 + ka * 32 + g * 8);
        #pragma unroll
        for (int Nt = 0; Nt < 2; ++Nt) {
            int c = cb * 128 + wcol * 32 + Nt * 16 + l15;
            pf[Nt] = *(const bf16x8*)(ptb + (size_t)rt * 32768 + c * 64 + ka * 32 + g * 8);
        }
        #pragma unroll
        for (int Mt = 0; Mt < 4; ++Mt)
            #pragma unroll
            for (int Nt = 0; Nt < 2; ++Nt)
                acc[Mt][Nt] = __builtin_amdgcn_mfma_f32_16x16x32_bf16(qf[Mt], pf[Nt], acc[Mt][Nt], 0, 0, 0);
    }

    __syncthreads();

    // ---- PV diag: acc += S(128x128) @ V_diag(128 s x cols) ----
    #pragma unroll
    for (int ks = 0; ks < 4; ++ks) {
        bf16x8 sf[4], vf[2];
        #pragma unroll
        for (int Mt = 0; Mt < 4; ++Mt) {
            int row = wr * 64 + Mt * 16 + l15;
            int slot = (ks * 4 + g) ^ (row & 15);
            sf[Mt] = *(const bf16x8*)&Slds[row * 128 + slot * 8];
        }
        #pragma unroll
        for (int Nt = 0; Nt < 2; ++Nt) {
            int c = cb * 128 + wcol * 32 + Nt * 16 + l15;
            vf[Nt] = *(const bf16x8*)(vt + (size_t)c * TT + rt * 128 + ks * 32 + g * 8);
        }
        #pragma unroll
        for (int Mt = 0; Mt < 4; ++Mt)
            #pragma unroll
            for (int Nt = 0; Nt < 2; ++Nt)
                acc[Mt][Nt] = __builtin_amdgcn_mfma_f32_16x16x32_bf16(sf[Mt], vf[Nt], acc[Mt][Nt], 0, 0, 0);
    }

    // ---- epilogue: out = x + acc (each element written exactly once) ----
    #pragma unroll
    for (int Mt = 0; Mt < 4; ++Mt) {
        #pragma unroll
        for (int Nt = 0; Nt < 2; ++Nt) {
            int col = cb * 128 + wcol * 32 + Nt * 16 + l15;
            #pragma unroll
            for (int jj = 0; jj < 4; ++jj) {
                int row = rt * 128 + wr * 64 + Mt * 16 + g * 4 + jj;
                out[(size_t)row * 512 + col] = x[(size_t)row * 512 + col] + acc[Mt][Nt][jj];
            }
        }
    }
}

extern "C" void kernel_launch(void* const* d_in, const int* in_sizes, int n_in,
                              void* d_out, int out_size, void* d_ws, size_t ws_size,
                              hipStream_t stream) {
    (void)in_sizes; (void)n_in; (void)out_size; (void)ws_size;
    const float* x    = (const float*)d_in[0];
    const float* xe   = (const float*)d_in[1];
    const float* lns  = (const float*)d_in[2];
    const float* lnb  = (const float*)d_in[3];
    const float* Wq   = (const float*)d_in[4];
    const float* Wk   = (const float*)d_in[5];
    const float* Wv   = (const float*)d_in[6];
    float* out = (float*)d_out;
    char* ws = (char*)d_ws;

    size_t off_xx   = 0;                                    // bf16 [8192][512]   8 MB
    size_t off_qk   = off_xx   + (size_t)TT * CC * 2;       // bf16 [8192][128]   2 MB
    size_t off_wqkt = off_qk   + (size_t)TT * 128 * 2;      // bf16 [128][512]
    size_t off_wvt  = off_wqkt + (size_t)128 * 512 * 2;     // bf16 [512][512]
    size_t off_vt   = off_wvt  + (size_t)512 * 512 * 2;     // bf16 [512][8192]   8 MB
    size_t off_xeb  = off_vt   + (size_t)TT * CC * 2;       // bf16 [8192][512]   8 MB
    size_t off_kt   = off_xeb  + (size_t)TT * CC * 2;       // bf16 [64][8192]    1 MB
    size_t off_gt   = off_kt   + (size_t)64 * TT * 2;       // f32  [128][512][64] 16.8 MB
    size_t off_ptb  = off_gt   + (size_t)128 * 32768 * 4;   // bf16 [64][512][64]  4.2 MB

    u16* xx   = (u16*)(ws + off_xx);
    u16* qk   = (u16*)(ws + off_qk);
    u16* wqkt = (u16*)(ws + off_wqkt);
    u16* wvt  = (u16*)(ws + off_wvt);
    u16* vt   = (u16*)(ws + off_vt);
    u16* xeb  = (u16*)(ws + off_xeb);
    u16* kt   = (u16*)(ws + off_kt);
    float* Gt = (float*)(ws + off_gt);
    u16* ptb  = (u16*)(ws + off_ptb);

    hipLaunchKernelGGL(lnw_kernel,      dim3(5376), dim3(256), 0, stream,
                       x, lns, lnb, Wq, Wk, Wv, xe, xx, wqkt, wvt, xeb);
    hipLaunchKernelGGL(qkv_gemm_kernel, dim3(768),  dim3(256), 0, stream,
                       xx, wqkt, xeb, wvt, qk, kt, vt);
    hipLaunchKernelGGL(gkv_kernel,      dim3(128),  dim3(512), 0, stream, vt, kt, Gt);
    hipLaunchKernelGGL(scan_kernel,     dim3(128),  dim3(256), 0, stream, Gt, ptb);
    hipLaunchKernelGGL(out_kernel,      dim3(256),  dim3(512), 0, stream, qk, ptb, vt, x, out);
}

// Round 19
// 62.791 us; speedup vs baseline: 3.6856x; 1.5548x over previous
//
#include <hip/hip_runtime.h>

#define TT 8192
#define CC 512

typedef unsigned short u16;
typedef unsigned int u32;
typedef __attribute__((ext_vector_type(8))) short bf16x8;
typedef __attribute__((ext_vector_type(4))) float f32x4;

#define VMCNT0() asm volatile("s_waitcnt vmcnt(0)" ::: "memory")
#define LGKM0()  asm volatile("s_waitcnt lgkmcnt(0)" ::: "memory")

__device__ __forceinline__ u16 f2bf(float f) {
    u32 u = __float_as_uint(f);
    return (u16)((u + 0x7FFFu + ((u >> 16) & 1u)) >> 16);
}

__device__ __forceinline__ void gld16(const u16* g, u16* l) {
    __builtin_amdgcn_global_load_lds(
        (const __attribute__((address_space(1))) u32*)g,
        (__attribute__((address_space(3))) u32*)l, 16, 0, 0);
}

// ---- Kernel 1: LN -> xx (bf16), weight transposes (q-cols pre-scaled 1/8), xe -> xeb ----
__global__ void lnw_kernel(const float* __restrict__ x,
                           const float* __restrict__ scale,
                           const float* __restrict__ bias,
                           const float* __restrict__ Wq,
                           const float* __restrict__ Wk,
                           const float* __restrict__ Wv,
                           const float* __restrict__ xe,
                           u16* __restrict__ xx,
                           u16* __restrict__ wqkt,
                           u16* __restrict__ wvt,
                           u16* __restrict__ xeb) {
    int b = blockIdx.x;
    if (b < 2048) {
        int row = b * 4 + (threadIdx.x >> 6);
        int l = threadIdx.x & 63;
        const float4* xr = (const float4*)(x + (size_t)row * CC);
        float4 a = xr[l * 2], c = xr[l * 2 + 1];
        float s = a.x + a.y + a.z + a.w + c.x + c.y + c.z + c.w;
        float q = a.x*a.x + a.y*a.y + a.z*a.z + a.w*a.w
                + c.x*c.x + c.y*c.y + c.z*c.z + c.w*c.w;
        #pragma unroll
        for (int m = 1; m < 64; m <<= 1) {
            s += __shfl_xor(s, m, 64);
            q += __shfl_xor(q, m, 64);
        }
        float mu = s * (1.0f / CC);
        float var = q * (1.0f / CC) - mu * mu;
        float rs = rsqrtf(var + 1e-5f);
        const float4* sc4 = (const float4*)scale;
        const float4* bi4 = (const float4*)bias;
        float4 s1 = sc4[l * 2], s2 = sc4[l * 2 + 1];
        float4 b1 = bi4[l * 2], b2 = bi4[l * 2 + 1];
        bf16x8 o;
        o[0] = (short)f2bf((a.x - mu) * rs * s1.x + b1.x);
        o[1] = (short)f2bf((a.y - mu) * rs * s1.y + b1.y);
        o[2] = (short)f2bf((a.z - mu) * rs * s1.z + b1.z);
        o[3] = (short)f2bf((a.w - mu) * rs * s1.w + b1.w);
        o[4] = (short)f2bf((c.x - mu) * rs * s2.x + b2.x);
        o[5] = (short)f2bf((c.y - mu) * rs * s2.y + b2.y);
        o[6] = (short)f2bf((c.z - mu) * rs * s2.z + b2.z);
        o[7] = (short)f2bf((c.w - mu) * rs * s2.w + b2.w);
        *(bf16x8*)(xx + (size_t)row * CC + l * 8) = o;
    } else if (b < 3328) {
        int tid = (b - 2048) * 256 + threadIdx.x;   // 0 .. 327679
        if (tid < 65536) {
            int c = tid >> 9, k = tid & 511;
            float w = (c < 64) ? Wq[k * 64 + c] * 0.125f : Wk[k * 64 + (c - 64)];
            wqkt[tid] = f2bf(w);
        } else {
            int i = tid - 65536;
            int c = i >> 9, k = i & 511;
            wvt[i] = f2bf(Wv[k * 512 + c]);
        }
    } else {
        size_t i = (size_t)(b - 3328) * 2048 + (size_t)threadIdx.x * 8;
        float4 a = *(const float4*)(xe + i);
        float4 c = *(const float4*)(xe + i + 4);
        bf16x8 o;
        o[0] = (short)f2bf(a.x); o[1] = (short)f2bf(a.y);
        o[2] = (short)f2bf(a.z); o[3] = (short)f2bf(a.w);
        o[4] = (short)f2bf(c.x); o[5] = (short)f2bf(c.y);
        o[6] = (short)f2bf(c.z); o[7] = (short)f2bf(c.w);
        *(bf16x8*)(xeb + i) = o;
    }
}

// ---- Kernel 2: staged GEMM. blocks 0..63: qk = xx@[Wq/8|Wk] (+kt); 64..319: vT = (xeb@Wv)^T ----
// M-tile 128, N-tile 128, BK=64; A/B gld16-DMA double-buffered (r11 schedule); 64KB LDS.
__global__ __launch_bounds__(512, 4) void qkv_gemm_kernel(const u16* __restrict__ xx,
                                                          const u16* __restrict__ wqkt,
                                                          const u16* __restrict__ xeb,
                                                          const u16* __restrict__ wvt,
                                                          u16* __restrict__ qk,
                                                          u16* __restrict__ kt,
                                                          u16* __restrict__ vt) {
    extern __shared__ u16 smem[];      // A: 2x8192 u16 @0 ; B: 2x8192 u16 @16384 ; tl aliases @0

    const int tid = threadIdx.x;
    const int w = tid >> 6, l = tid & 63;
    const int l15 = l & 15, g = l >> 4;
    const int wr = w >> 2, wc = w & 3;

    const bool isqk = blockIdx.x < 64;
    int r0, c0;
    const u16 *Asrc, *Bsrc;
    if (isqk) { r0 = blockIdx.x * 128; c0 = 0; Asrc = xx; Bsrc = wqkt; }
    else {
        int b2 = blockIdx.x - 64;
        r0 = (b2 >> 2) * 128; c0 = (b2 & 3) * 128; Asrc = xeb; Bsrc = wvt;
    }

    const int drow = tid >> 3, sl = tid & 7;
    #define A_DMA(KK, B) { \
        _Pragma("unroll") \
        for (int i = 0; i < 2; ++i) { \
            int r = i * 64 + drow; \
            gld16(Asrc + (size_t)(r0 + r) * CC + (KK) * 64 + ((sl ^ (r & 7)) << 3), \
                  smem + (B) * 8192 + r * 64 + sl * 8); \
        } }
    #define B_DMA(KK, B) { \
        _Pragma("unroll") \
        for (int i = 0; i < 2; ++i) { \
            int r = i * 64 + drow; \
            gld16(Bsrc + (size_t)(c0 + r) * CC + (KK) * 64 + ((sl ^ (r & 7)) << 3), \
                  smem + 16384 + (B) * 8192 + r * 64 + sl * 8); \
        } }

    f32x4 acc[4][2];
    #pragma unroll
    for (int m = 0; m < 4; ++m)
        #pragma unroll
        for (int n = 0; n < 2; ++n) acc[m][n] = (f32x4){0.f, 0.f, 0.f, 0.f};

    A_DMA(0, 0); B_DMA(0, 0);

    int cur = 0;
    for (int kk = 0; kk < 8; ++kk) {
        VMCNT0();
        LGKM0();
        __builtin_amdgcn_s_barrier();
        if (kk < 7) { A_DMA(kk + 1, cur ^ 1); B_DMA(kk + 1, cur ^ 1); }

        const u16* Ab = smem + cur * 8192;
        const u16* Bb = smem + 16384 + cur * 8192;
        __builtin_amdgcn_s_setprio(1);
        #pragma unroll
        for (int ka = 0; ka < 2; ++ka) {
            bf16x8 af[4], bfr[2];
            #pragma unroll
            for (int Mt = 0; Mt < 4; ++Mt) {
                int r = wr * 64 + Mt * 16 + l15;
                int ph = (ka * 4 + g) ^ (r & 7);
                af[Mt] = *(const bf16x8*)&Ab[r * 64 + ph * 8];
            }
            #pragma unroll
            for (int Nt = 0; Nt < 2; ++Nt) {
                int c = wc * 32 + Nt * 16 + l15;
                int ph = (ka * 4 + g) ^ (c & 7);
                bfr[Nt] = *(const bf16x8*)&Bb[c * 64 + ph * 8];
            }
            #pragma unroll
            for (int Mt = 0; Mt < 4; ++Mt)
                #pragma unroll
                for (int Nt = 0; Nt < 2; ++Nt)
                    acc[Mt][Nt] = __builtin_amdgcn_mfma_f32_16x16x32_bf16(af[Mt], bfr[Nt], acc[Mt][Nt], 0, 0, 0);
        }
        __builtin_amdgcn_s_setprio(0);
        cur ^= 1;
    }

    if (isqk) {
        // qk tile store (row-major) + kt transpose via LDS (alias staging)
        #pragma unroll
        for (int Mt = 0; Mt < 4; ++Mt) {
            #pragma unroll
            for (int Nt = 0; Nt < 2; ++Nt) {
                int col = wc * 32 + Nt * 16 + l15;
                #pragma unroll
                for (int jj = 0; jj < 4; ++jj) {
                    int row = wr * 64 + Mt * 16 + g * 4 + jj;
                    qk[(size_t)(r0 + row) * 128 + col] = f2bf(acc[Mt][Nt][jj]);
                }
            }
        }
        __syncthreads();
        u16* tl = smem;                     // [64 a][136]
        if (wc >= 2) {
            #pragma unroll
            for (int Mt = 0; Mt < 4; ++Mt) {
                #pragma unroll
                for (int Nt = 0; Nt < 2; ++Nt) {
                    int a = (wc - 2) * 32 + Nt * 16 + l15;
                    #pragma unroll
                    for (int jj = 0; jj < 4; ++jj) {
                        int row = wr * 64 + Mt * 16 + g * 4 + jj;
                        tl[a * 136 + row] = f2bf(acc[Mt][Nt][jj]);
                    }
                }
            }
        }
        __syncthreads();
        #pragma unroll
        for (int i = 0; i < 2; ++i) {
            int chunk = i * 512 + tid;      // 0..1023
            int a = chunk >> 4, r8 = chunk & 15;
            *(bf16x8*)(kt + (size_t)a * TT + r0 + r8 * 8) = *(const bf16x8*)&tl[a * 136 + r8 * 8];
        }
    } else {
        // vT store via LDS transpose (alias staging)
        __syncthreads();
        u16* tl = smem;                     // [128 c][136]
        #pragma unroll
        for (int Mt = 0; Mt < 4; ++Mt) {
            #pragma unroll
            for (int Nt = 0; Nt < 2; ++Nt) {
                int col = wc * 32 + Nt * 16 + l15;
                #pragma unroll
                for (int jj = 0; jj < 4; ++jj) {
                    int row = wr * 64 + Mt * 16 + g * 4 + jj;
                    tl[col * 136 + row] = f2bf(acc[Mt][Nt][jj]);
                }
            }
        }
        __syncthreads();
        #pragma unroll
        for (int i = 0; i < 4; ++i) {
            int chunk = i * 512 + tid;      // 0..2047
            int c = chunk >> 4, r8 = chunk & 15;
            *(bf16x8*)(vt + (size_t)(c0 + c) * TT + r0 + r8 * 8) = *(const bf16x8*)&tl[c * 136 + r8 * 8];
        }
    }
    #undef A_DMA
    #undef B_DMA
}

// ---- Kernel 3: Gt[j][c][a] = sum_{s in tile j} V[s][c] K[s][a]  (f32), j = 0..127 ----
__global__ __launch_bounds__(512) void gkv_kernel(const u16* __restrict__ vt,
                                                  const u16* __restrict__ kt,
                                                  float* __restrict__ Gt) {
    int j = blockIdx.x;
    int w = threadIdx.x >> 6, l = threadIdx.x & 63;
    int l15 = l & 15, g = l >> 4;
    int c0 = w * 64;

    f32x4 acc[4][4];
    #pragma unroll
    for (int m = 0; m < 4; ++m)
        #pragma unroll
        for (int n = 0; n < 4; ++n) acc[m][n] = (f32x4){0.f, 0.f, 0.f, 0.f};

    #pragma unroll
    for (int ka = 0; ka < 2; ++ka) {
        int k = j * 64 + ka * 32 + g * 8;
        bf16x8 af[4], bfr[4];
        #pragma unroll
        for (int Mt = 0; Mt < 4; ++Mt)
            af[Mt] = *(const bf16x8*)(vt + (size_t)(c0 + Mt * 16 + l15) * TT + k);
        #pragma unroll
        for (int Nt = 0; Nt < 4; ++Nt)
            bfr[Nt] = *(const bf16x8*)(kt + (size_t)(Nt * 16 + l15) * TT + k);
        #pragma unroll
        for (int Mt = 0; Mt < 4; ++Mt)
            #pragma unroll
            for (int Nt = 0; Nt < 4; ++Nt)
                acc[Mt][Nt] = __builtin_amdgcn_mfma_f32_16x16x32_bf16(af[Mt], bfr[Nt], acc[Mt][Nt], 0, 0, 0);
    }

    float* gp = Gt + (size_t)j * 32768;
    #pragma unroll
    for (int Mt = 0; Mt < 4; ++Mt) {
        #pragma unroll
        for (int Nt = 0; Nt < 4; ++Nt) {
            int a = Nt * 16 + l15;
            #pragma unroll
            for (int jj = 0; jj < 4; ++jj) {
                int c = c0 + Mt * 16 + g * 4 + jj;
                gp[c * 64 + a] = acc[Mt][Nt][jj];
            }
        }
    }
}

// ---- Kernel 4: scan -> ptb[i][c][a] = bf16( sum_{j < 2i} Gt[j][c][a] ), i = 0..63 ----
__global__ __launch_bounds__(256) void scan_kernel(const float* __restrict__ Gt,
                                                   u16* __restrict__ ptb) {
    int e = blockIdx.x * 256 + threadIdx.x;   // 0..32767
    float acc = 0.f;
    ptb[e] = 0;
    for (int i = 1; i < 64; ++i) {
        acc += Gt[(size_t)(2 * i - 2) * 32768 + e] + Gt[(size_t)(2 * i - 1) * 32768 + e];
        ptb[(size_t)i * 32768 + e] = f2bf(acc);
    }
}

// ---- Kernel 5: out = x + Q_i @ P_i + tril(Q_i K_diag^T) @ V_diag ; single-shot, 1 barrier ----
__global__ __launch_bounds__(512) void out_kernel(const u16* __restrict__ qk,
                                                  const u16* __restrict__ ptb,
                                                  const u16* __restrict__ vt,
                                                  const float* __restrict__ x,
                                                  float* __restrict__ out) {
    __shared__ u16 Slds[128 * 128];   // [r][128 s], 16-slot XOR swizzle, 32KB

    const int tid = threadIdx.x;
    const int w = tid >> 6, l = tid & 63;
    const int l15 = l & 15, g = l >> 4;
    const int wr = w >> 2, wcol = w & 3;

    const int rt = (int)blockIdx.x >> 2;
    const int cb = (int)blockIdx.x & 3;

    f32x4 acc[4][2];
    #pragma unroll
    for (int m = 0; m < 4; ++m)
        #pragma unroll
        for (int n = 0; n < 2; ++n) acc[m][n] = (f32x4){0.f, 0.f, 0.f, 0.f};

    // ---- diag QK^T: wave w computes S rows [w*16, +16) x 128 s ----
    const int dq = rt * 128 + w * 16 + l15;
    const bf16x8 qa0 = *(const bf16x8*)(qk + (size_t)dq * 128 + g * 8);
    const bf16x8 qa1 = *(const bf16x8*)(qk + (size_t)dq * 128 + 32 + g * 8);
    #pragma unroll
    for (int Nt = 0; Nt < 8; ++Nt) {
        int scol = Nt * 16 + l15;
        f32x4 sacc = (f32x4){0.f, 0.f, 0.f, 0.f};
        #pragma unroll
        for (int ka = 0; ka < 2; ++ka) {
            bf16x8 kf = *(const bf16x8*)(qk + (size_t)(rt * 128 + scol) * 128 + 64 + ka * 32 + g * 8);
            sacc = __builtin_amdgcn_mfma_f32_16x16x32_bf16(ka ? qa1 : qa0, kf, sacc, 0, 0, 0);
        }
        #pragma unroll
        for (int jj = 0; jj < 4; ++jj) {
            int row = w * 16 + g * 4 + jj;
            float val = (scol > row) ? 0.f : sacc[jj];
            int slot = (scol >> 3) ^ (row & 15);
            Slds[row * 128 + slot * 8 + (scol & 7)] = f2bf(val);
        }
    }

    // ---- main: acc += Q_i @ P_i (K=64) ----
    #pragma unroll
    for (int ka = 0; ka < 2; ++ka) {
        bf16x8 qf[4], pf[2];
        #pragma unroll
        for (int Mt = 0; Mt < 4; ++Mt)
            qf[Mt] = *(const bf16x8*)(qk + (size_t)(rt * 128 + wr * 64 + Mt * 16 + l15) * 128 + ka * 32 + g * 8);
        #pragma unroll
        for (int Nt = 0; Nt < 2; ++Nt) {
            int c = cb * 128 + wcol * 32 + Nt * 16 + l15;
            pf[Nt] = *(const bf16x8*)(ptb + (size_t)rt * 32768 + c * 64 + ka * 32 + g * 8);
        }
        #pragma unroll
        for (int Mt = 0; Mt < 4; ++Mt)
            #pragma unroll
            for (int Nt = 0; Nt < 2; ++Nt)
                acc[Mt][Nt] = __builtin_amdgcn_mfma_f32_16x16x32_bf16(qf[Mt], pf[Nt], acc[Mt][Nt], 0, 0, 0);
    }

    __syncthreads();

    // ---- PV diag: acc += S(128x128) @ V_diag(128 s x cols) ----
    #pragma unroll
    for (int ks = 0; ks < 4; ++ks) {
        bf16x8 sf[4], vf[2];
        #pragma unroll
        for (int Mt = 0; Mt < 4; ++Mt) {
            int row = wr * 64 + Mt * 16 + l15;
            int slot = (ks * 4 + g) ^ (row & 15);
            sf[Mt] = *(const bf16x8*)&Slds[row * 128 + slot * 8];
        }
        #pragma unroll
        for (int Nt = 0; Nt < 2; ++Nt) {
            int c = cb * 128 + wcol * 32 + Nt * 16 + l15;
            vf[Nt] = *(const bf16x8*)(vt + (size_t)c * TT + rt * 128 + ks * 32 + g * 8);
        }
        #pragma unroll
        for (int Mt = 0; Mt < 4; ++Mt)
            #pragma unroll
            for (int Nt = 0; Nt < 2; ++Nt)
                acc[Mt][Nt] = __builtin_amdgcn_mfma_f32_16x16x32_bf16(sf[Mt], vf[Nt], acc[Mt][Nt], 0, 0, 0);
    }

    // ---- epilogue: out = x + acc (each element written exactly once) ----
    #pragma unroll
    for (int Mt = 0; Mt < 4; ++Mt) {
        #pragma unroll
        for (int Nt = 0; Nt < 2; ++Nt) {
            int col = cb * 128 + wcol * 32 + Nt * 16 + l15;
            #pragma unroll
            for (int jj = 0; jj < 4; ++jj) {
                int row = rt * 128 + wr * 64 + Mt * 16 + g * 4 + jj;
                out[(size_t)row * 512 + col] = x[(size_t)row * 512 + col] + acc[Mt][Nt][jj];
            }
        }
    }
}

extern "C" void kernel_launch(void* const* d_in, const int* in_sizes, int n_in,
                              void* d_out, int out_size, void* d_ws, size_t ws_size,
                              hipStream_t stream) {
    (void)in_sizes; (void)n_in; (void)out_size; (void)ws_size;
    const float* x    = (const float*)d_in[0];
    const float* xe   = (const float*)d_in[1];
    const float* lns  = (const float*)d_in[2];
    const float* lnb  = (const float*)d_in[3];
    const float* Wq   = (const float*)d_in[4];
    const float* Wk   = (const float*)d_in[5];
    const float* Wv   = (const float*)d_in[6];
    float* out = (float*)d_out;
    char* ws = (char*)d_ws;

    size_t off_xx   = 0;                                    // bf16 [8192][512]   8 MB
    size_t off_qk   = off_xx   + (size_t)TT * CC * 2;       // bf16 [8192][128]   2 MB
    size_t off_wqkt = off_qk   + (size_t)TT * 128 * 2;      // bf16 [128][512]
    size_t off_wvt  = off_wqkt + (size_t)128 * 512 * 2;     // bf16 [512][512]
    size_t off_vt   = off_wvt  + (size_t)512 * 512 * 2;     // bf16 [512][8192]   8 MB
    size_t off_xeb  = off_vt   + (size_t)TT * CC * 2;       // bf16 [8192][512]   8 MB
    size_t off_kt   = off_xeb  + (size_t)TT * CC * 2;       // bf16 [64][8192]    1 MB
    size_t off_gt   = off_kt   + (size_t)64 * TT * 2;       // f32  [128][512][64] 16.8 MB
    size_t off_ptb  = off_gt   + (size_t)128 * 32768 * 4;   // bf16 [64][512][64]  4.2 MB

    u16* xx   = (u16*)(ws + off_xx);
    u16* qk   = (u16*)(ws + off_qk);
    u16* wqkt = (u16*)(ws + off_wqkt);
    u16* wvt  = (u16*)(ws + off_wvt);
    u16* vt   = (u16*)(ws + off_vt);
    u16* xeb  = (u16*)(ws + off_xeb);
    u16* kt   = (u16*)(ws + off_kt);
    float* Gt = (float*)(ws + off_gt);
    u16* ptb  = (u16*)(ws + off_ptb);

    const size_t qkv_lds = 65536;   // 64 KB: A dbuf 32K + B dbuf 32K (transpose aliases)

    hipLaunchKernelGGL(lnw_kernel,      dim3(5376), dim3(256), 0, stream,
                       x, lns, lnb, Wq, Wk, Wv, xe, xx, wqkt, wvt, xeb);
    hipLaunchKernelGGL(qkv_gemm_kernel, dim3(320),  dim3(512), qkv_lds, stream,
                       xx, wqkt, xeb, wvt, qk, kt, vt);
    hipLaunchKernelGGL(gkv_kernel,      dim3(128),  dim3(512), 0, stream, vt, kt, Gt);
    hipLaunchKernelGGL(scan_kernel,     dim3(128),  dim3(256), 0, stream, Gt, ptb);
    hipLaunchKernelGGL(out_kernel,      dim3(256),  dim3(512), 0, stream, qk, ptb, vt, x, out);
}

// Round 20
// 54.291 us; speedup vs baseline: 4.2626x; 1.1566x over previous
//
#include <hip/hip_runtime.h>

#define TT 8192
#define CC 512

typedef unsigned short u16;
typedef unsigned int u32;
typedef __attribute__((ext_vector_type(8))) short bf16x8;
typedef __attribute__((ext_vector_type(4))) float f32x4;

#define VMCNT0() asm volatile("s_waitcnt vmcnt(0)" ::: "memory")
#define LGKM0()  asm volatile("s_waitcnt lgkmcnt(0)" ::: "memory")

__device__ __forceinline__ u16 f2bf(float f) {
    u32 u = __float_as_uint(f);
    return (u16)((u + 0x7FFFu + ((u >> 16) & 1u)) >> 16);
}

__device__ __forceinline__ void gld16(const u16* g, u16* l) {
    __builtin_amdgcn_global_load_lds(
        (const __attribute__((address_space(1))) u32*)g,
        (__attribute__((address_space(3))) u32*)l, 16, 0, 0);
}

// ---- Kernel 1: LN -> xx (bf16), weight transposes (q-cols pre-scaled 1/8), xe -> xeb ----
__global__ void lnw_kernel(const float* __restrict__ x,
                           const float* __restrict__ scale,
                           const float* __restrict__ bias,
                           const float* __restrict__ Wq,
                           const float* __restrict__ Wk,
                           const float* __restrict__ Wv,
                           const float* __restrict__ xe,
                           u16* __restrict__ xx,
                           u16* __restrict__ wqkt,
                           u16* __restrict__ wvt,
                           u16* __restrict__ xeb) {
    int b = blockIdx.x;
    if (b < 2048) {
        int row = b * 4 + (threadIdx.x >> 6);
        int l = threadIdx.x & 63;
        const float4* xr = (const float4*)(x + (size_t)row * CC);
        float4 a = xr[l * 2], c = xr[l * 2 + 1];
        float s = a.x + a.y + a.z + a.w + c.x + c.y + c.z + c.w;
        float q = a.x*a.x + a.y*a.y + a.z*a.z + a.w*a.w
                + c.x*c.x + c.y*c.y + c.z*c.z + c.w*c.w;
        #pragma unroll
        for (int m = 1; m < 64; m <<= 1) {
            s += __shfl_xor(s, m, 64);
            q += __shfl_xor(q, m, 64);
        }
        float mu = s * (1.0f / CC);
        float var = q * (1.0f / CC) - mu * mu;
        float rs = rsqrtf(var + 1e-5f);
        const float4* sc4 = (const float4*)scale;
        const float4* bi4 = (const float4*)bias;
        float4 s1 = sc4[l * 2], s2 = sc4[l * 2 + 1];
        float4 b1 = bi4[l * 2], b2 = bi4[l * 2 + 1];
        bf16x8 o;
        o[0] = (short)f2bf((a.x - mu) * rs * s1.x + b1.x);
        o[1] = (short)f2bf((a.y - mu) * rs * s1.y + b1.y);
        o[2] = (short)f2bf((a.z - mu) * rs * s1.z + b1.z);
        o[3] = (short)f2bf((a.w - mu) * rs * s1.w + b1.w);
        o[4] = (short)f2bf((c.x - mu) * rs * s2.x + b2.x);
        o[5] = (short)f2bf((c.y - mu) * rs * s2.y + b2.y);
        o[6] = (short)f2bf((c.z - mu) * rs * s2.z + b2.z);
        o[7] = (short)f2bf((c.w - mu) * rs * s2.w + b2.w);
        *(bf16x8*)(xx + (size_t)row * CC + l * 8) = o;
    } else if (b < 3328) {
        int tid = (b - 2048) * 256 + threadIdx.x;   // 0 .. 327679
        if (tid < 65536) {
            int c = tid >> 9, k = tid & 511;
            float w = (c < 64) ? Wq[k * 64 + c] * 0.125f : Wk[k * 64 + (c - 64)];
            wqkt[tid] = f2bf(w);
        } else {
            int i = tid - 65536;
            int c = i >> 9, k = i & 511;
            wvt[i] = f2bf(Wv[k * 512 + c]);
        }
    } else {
        size_t i = (size_t)(b - 3328) * 2048 + (size_t)threadIdx.x * 8;
        float4 a = *(const float4*)(xe + i);
        float4 c = *(const float4*)(xe + i + 4);
        bf16x8 o;
        o[0] = (short)f2bf(a.x); o[1] = (short)f2bf(a.y);
        o[2] = (short)f2bf(a.z); o[3] = (short)f2bf(a.w);
        o[4] = (short)f2bf(c.x); o[5] = (short)f2bf(c.y);
        o[6] = (short)f2bf(c.z); o[7] = (short)f2bf(c.w);
        *(bf16x8*)(xeb + i) = o;
    }
}

// ---- Kernel 2: staged GEMM. blocks 0..63: qk = xx@[Wq/8|Wk] (+kt); 64..319: vT = (xeb@Wv)^T ----
__global__ __launch_bounds__(512, 4) void qkv_gemm_kernel(const u16* __restrict__ xx,
                                                          const u16* __restrict__ wqkt,
                                                          const u16* __restrict__ xeb,
                                                          const u16* __restrict__ wvt,
                                                          u16* __restrict__ qk,
                                                          u16* __restrict__ kt,
                                                          u16* __restrict__ vt) {
    extern __shared__ u16 smem[];      // A: 2x8192 u16 @0 ; B: 2x8192 u16 @16384 ; tl aliases @0

    const int tid = threadIdx.x;
    const int w = tid >> 6, l = tid & 63;
    const int l15 = l & 15, g = l >> 4;
    const int wr = w >> 2, wc = w & 3;

    const bool isqk = blockIdx.x < 64;
    int r0, c0;
    const u16 *Asrc, *Bsrc;
    if (isqk) { r0 = blockIdx.x * 128; c0 = 0; Asrc = xx; Bsrc = wqkt; }
    else {
        int b2 = blockIdx.x - 64;
        r0 = (b2 >> 2) * 128; c0 = (b2 & 3) * 128; Asrc = xeb; Bsrc = wvt;
    }

    const int drow = tid >> 3, sl = tid & 7;
    #define A_DMA(KK, B) { \
        _Pragma("unroll") \
        for (int i = 0; i < 2; ++i) { \
            int r = i * 64 + drow; \
            gld16(Asrc + (size_t)(r0 + r) * CC + (KK) * 64 + ((sl ^ (r & 7)) << 3), \
                  smem + (B) * 8192 + r * 64 + sl * 8); \
        } }
    #define B_DMA(KK, B) { \
        _Pragma("unroll") \
        for (int i = 0; i < 2; ++i) { \
            int r = i * 64 + drow; \
            gld16(Bsrc + (size_t)(c0 + r) * CC + (KK) * 64 + ((sl ^ (r & 7)) << 3), \
                  smem + 16384 + (B) * 8192 + r * 64 + sl * 8); \
        } }

    f32x4 acc[4][2];
    #pragma unroll
    for (int m = 0; m < 4; ++m)
        #pragma unroll
        for (int n = 0; n < 2; ++n) acc[m][n] = (f32x4){0.f, 0.f, 0.f, 0.f};

    A_DMA(0, 0); B_DMA(0, 0);

    int cur = 0;
    for (int kk = 0; kk < 8; ++kk) {
        VMCNT0();
        LGKM0();
        __builtin_amdgcn_s_barrier();
        if (kk < 7) { A_DMA(kk + 1, cur ^ 1); B_DMA(kk + 1, cur ^ 1); }

        const u16* Ab = smem + cur * 8192;
        const u16* Bb = smem + 16384 + cur * 8192;
        __builtin_amdgcn_s_setprio(1);
        #pragma unroll
        for (int ka = 0; ka < 2; ++ka) {
            bf16x8 af[4], bfr[2];
            #pragma unroll
            for (int Mt = 0; Mt < 4; ++Mt) {
                int r = wr * 64 + Mt * 16 + l15;
                int ph = (ka * 4 + g) ^ (r & 7);
                af[Mt] = *(const bf16x8*)&Ab[r * 64 + ph * 8];
            }
            #pragma unroll
            for (int Nt = 0; Nt < 2; ++Nt) {
                int c = wc * 32 + Nt * 16 + l15;
                int ph = (ka * 4 + g) ^ (c & 7);
                bfr[Nt] = *(const bf16x8*)&Bb[c * 64 + ph * 8];
            }
            #pragma unroll
            for (int Mt = 0; Mt < 4; ++Mt)
                #pragma unroll
                for (int Nt = 0; Nt < 2; ++Nt)
                    acc[Mt][Nt] = __builtin_amdgcn_mfma_f32_16x16x32_bf16(af[Mt], bfr[Nt], acc[Mt][Nt], 0, 0, 0);
        }
        __builtin_amdgcn_s_setprio(0);
        cur ^= 1;
    }

    if (isqk) {
        #pragma unroll
        for (int Mt = 0; Mt < 4; ++Mt) {
            #pragma unroll
            for (int Nt = 0; Nt < 2; ++Nt) {
                int col = wc * 32 + Nt * 16 + l15;
                #pragma unroll
                for (int jj = 0; jj < 4; ++jj) {
                    int row = wr * 64 + Mt * 16 + g * 4 + jj;
                    qk[(size_t)(r0 + row) * 128 + col] = f2bf(acc[Mt][Nt][jj]);
                }
            }
        }
        __syncthreads();
        u16* tl = smem;                     // [64 a][136]
        if (wc >= 2) {
            #pragma unroll
            for (int Mt = 0; Mt < 4; ++Mt) {
                #pragma unroll
                for (int Nt = 0; Nt < 2; ++Nt) {
                    int a = (wc - 2) * 32 + Nt * 16 + l15;
                    #pragma unroll
                    for (int jj = 0; jj < 4; ++jj) {
                        int row = wr * 64 + Mt * 16 + g * 4 + jj;
                        tl[a * 136 + row] = f2bf(acc[Mt][Nt][jj]);
                    }
                }
            }
        }
        __syncthreads();
        #pragma unroll
        for (int i = 0; i < 2; ++i) {
            int chunk = i * 512 + tid;      // 0..1023
            int a = chunk >> 4, r8 = chunk & 15;
            *(bf16x8*)(kt + (size_t)a * TT + r0 + r8 * 8) = *(const bf16x8*)&tl[a * 136 + r8 * 8];
        }
    } else {
        __syncthreads();
        u16* tl = smem;                     // [128 c][136]
        #pragma unroll
        for (int Mt = 0; Mt < 4; ++Mt) {
            #pragma unroll
            for (int Nt = 0; Nt < 2; ++Nt) {
                int col = wc * 32 + Nt * 16 + l15;
                #pragma unroll
                for (int jj = 0; jj < 4; ++jj) {
                    int row = wr * 64 + Mt * 16 + g * 4 + jj;
                    tl[col * 136 + row] = f2bf(acc[Mt][Nt][jj]);
                }
            }
        }
        __syncthreads();
        #pragma unroll
        for (int i = 0; i < 4; ++i) {
            int chunk = i * 512 + tid;      // 0..2047
            int c = chunk >> 4, r8 = chunk & 15;
            *(bf16x8*)(vt + (size_t)(c0 + c) * TT + r0 + r8 * 8) = *(const bf16x8*)&tl[c * 136 + r8 * 8];
        }
    }
    #undef A_DMA
    #undef B_DMA
}

// ---- Kernel 3: H[m][c][a] = sum_{s in rows [m*128,(m+1)*128)} V[s][c] K[s][a]  (f32), m=0..63 ----
__global__ __launch_bounds__(512) void gkv_kernel(const u16* __restrict__ vt,
                                                  const u16* __restrict__ kt,
                                                  float* __restrict__ H) {
    int m = blockIdx.x >> 2, cq = blockIdx.x & 3;
    int w = threadIdx.x >> 6, l = threadIdx.x & 63;
    int l15 = l & 15, g = l >> 4;
    int c0 = cq * 128 + (w >> 1) * 32;
    int a0 = (w & 1) * 32;

    f32x4 acc[2][2];
    #pragma unroll
    for (int i = 0; i < 2; ++i)
        #pragma unroll
        for (int n = 0; n < 2; ++n) acc[i][n] = (f32x4){0.f, 0.f, 0.f, 0.f};

    #pragma unroll
    for (int ka = 0; ka < 4; ++ka) {
        int k = m * 128 + ka * 32 + g * 8;
        bf16x8 af[2], bfr[2];
        #pragma unroll
        for (int Mt = 0; Mt < 2; ++Mt)
            af[Mt] = *(const bf16x8*)(vt + (size_t)(c0 + Mt * 16 + l15) * TT + k);
        #pragma unroll
        for (int Nt = 0; Nt < 2; ++Nt)
            bfr[Nt] = *(const bf16x8*)(kt + (size_t)(a0 + Nt * 16 + l15) * TT + k);
        #pragma unroll
        for (int Mt = 0; Mt < 2; ++Mt)
            #pragma unroll
            for (int Nt = 0; Nt < 2; ++Nt)
                acc[Mt][Nt] = __builtin_amdgcn_mfma_f32_16x16x32_bf16(af[Mt], bfr[Nt], acc[Mt][Nt], 0, 0, 0);
    }

    float* hp = H + (size_t)m * 32768;
    #pragma unroll
    for (int Mt = 0; Mt < 2; ++Mt) {
        #pragma unroll
        for (int Nt = 0; Nt < 2; ++Nt) {
            int a = a0 + Nt * 16 + l15;
            #pragma unroll
            for (int jj = 0; jj < 4; ++jj) {
                int c = c0 + Mt * 16 + g * 4 + jj;
                hp[c * 64 + a] = acc[Mt][Nt][jj];
            }
        }
    }
}

// ---- Kernel 4a: Asum[g][e] = sum_{t<8} H[8g+t][e],  g=0..7 ----
__global__ __launch_bounds__(256) void scanA_kernel(const float* __restrict__ H,
                                                    float* __restrict__ Asum) {
    int idx = blockIdx.x * 256 + threadIdx.x;    // 0..262143
    int g = idx >> 15, e = idx & 32767;
    float s = 0.f;
    #pragma unroll
    for (int t = 0; t < 8; ++t) s += H[(size_t)(8 * g + t) * 32768 + e];
    Asum[(size_t)g * 32768 + e] = s;
}

// ---- Kernel 4b: ptb[i][e] = bf16( sum_{m<i} H[m][e] ), via group base + 8-deep serial ----
__global__ __launch_bounds__(256) void scanB_kernel(const float* __restrict__ H,
                                                    const float* __restrict__ Asum,
                                                    u16* __restrict__ ptb) {
    int idx = blockIdx.x * 256 + threadIdx.x;    // 0..262143
    int g = idx >> 15, e = idx & 32767;
    float acc = 0.f;
    for (int g2 = 0; g2 < g; ++g2) acc += Asum[(size_t)g2 * 32768 + e];
    ptb[(size_t)(8 * g) * 32768 + e] = f2bf(acc);
    #pragma unroll
    for (int t = 1; t < 8; ++t) {
        acc += H[(size_t)(8 * g + t - 1) * 32768 + e];
        ptb[(size_t)(8 * g + t) * 32768 + e] = f2bf(acc);
    }
}

// ---- Kernel 5: out = x + Q_i @ P_i + tril(Q_i K_diag^T) @ V_diag ; single-shot, 1 barrier ----
__global__ __launch_bounds__(512) void out_kernel(const u16* __restrict__ qk,
                                                  const u16* __restrict__ ptb,
                                                  const u16* __restrict__ vt,
                                                  const float* __restrict__ x,
                                                  float* __restrict__ out) {
    __shared__ u16 Slds[128 * 128];   // [r][128 s], 16-slot XOR swizzle, 32KB

    const int tid = threadIdx.x;
    const int w = tid >> 6, l = tid & 63;
    const int l15 = l & 15, g = l >> 4;
    const int wr = w >> 2, wcol = w & 3;

    const int rt = (int)blockIdx.x >> 2;
    const int cb = (int)blockIdx.x & 3;

    f32x4 acc[4][2];
    #pragma unroll
    for (int m = 0; m < 4; ++m)
        #pragma unroll
        for (int n = 0; n < 2; ++n) acc[m][n] = (f32x4){0.f, 0.f, 0.f, 0.f};

    // ---- diag QK^T: wave w computes S rows [w*16, +16) x 128 s ----
    const int dq = rt * 128 + w * 16 + l15;
    const bf16x8 qa0 = *(const bf16x8*)(qk + (size_t)dq * 128 + g * 8);
    const bf16x8 qa1 = *(const bf16x8*)(qk + (size_t)dq * 128 + 32 + g * 8);
    #pragma unroll
    for (int Nt = 0; Nt < 8; ++Nt) {
        int scol = Nt * 16 + l15;
        f32x4 sacc = (f32x4){0.f, 0.f, 0.f, 0.f};
        #pragma unroll
        for (int ka = 0; ka < 2; ++ka) {
            bf16x8 kf = *(const bf16x8*)(qk + (size_t)(rt * 128 + scol) * 128 + 64 + ka * 32 + g * 8);
            sacc = __builtin_amdgcn_mfma_f32_16x16x32_bf16(ka ? qa1 : qa0, kf, sacc, 0, 0, 0);
        }
        #pragma unroll
        for (int jj = 0; jj < 4; ++jj) {
            int row = w * 16 + g * 4 + jj;
            float val = (scol > row) ? 0.f : sacc[jj];
            int slot = (scol >> 3) ^ (row & 15);
            Slds[row * 128 + slot * 8 + (scol & 7)] = f2bf(val);
        }
    }

    // ---- main: acc += Q_i @ P_i (K=64) ----
    #pragma unroll
    for (int ka = 0; ka < 2; ++ka) {
        bf16x8 qf[4], pf[2];
        #pragma unroll
        for (int Mt = 0; Mt < 4; ++Mt)
            qf[Mt] = *(const bf16x8*)(qk + (size_t)(rt * 128 + wr * 64 + Mt * 16 + l15) * 128 + ka * 32 + g * 8);
        #pragma unroll
        for (int Nt = 0; Nt < 2; ++Nt) {
            int c = cb * 128 + wcol * 32 + Nt * 16 + l15;
            pf[Nt] = *(const bf16x8*)(ptb + (size_t)rt * 32768 + c * 64 + ka * 32 + g * 8);
        }
        #pragma unroll
        for (int Mt = 0; Mt < 4; ++Mt)
            #pragma unroll
            for (int Nt = 0; Nt < 2; ++Nt)
                acc[Mt][Nt] = __builtin_amdgcn_mfma_f32_16x16x32_bf16(qf[Mt], pf[Nt], acc[Mt][Nt], 0, 0, 0);
    }

    __syncthreads();

    // ---- PV diag: acc += S(128x128) @ V_diag(128 s x cols) ----
    #pragma unroll
    for (int ks = 0; ks < 4; ++ks) {
        bf16x8 sf[4], vf[2];
        #pragma unroll
        for (int Mt = 0; Mt < 4; ++Mt) {
            int row = wr * 64 + Mt * 16 + l15;
            int slot = (ks * 4 + g) ^ (row & 15);
            sf[Mt] = *(const bf16x8*)&Slds[row * 128 + slot * 8];
        }
        #pragma unroll
        for (int Nt = 0; Nt < 2; ++Nt) {
            int c = cb * 128 + wcol * 32 + Nt * 16 + l15;
            vf[Nt] = *(const bf16x8*)(vt + (size_t)c * TT + rt * 128 + ks * 32 + g * 8);
        }
        #pragma unroll
        for (int Mt = 0; Mt < 4; ++Mt)
            #pragma unroll
            for (int Nt = 0; Nt < 2; ++Nt)
                acc[Mt][Nt] = __builtin_amdgcn_mfma_f32_16x16x32_bf16(sf[Mt], vf[Nt], acc[Mt][Nt], 0, 0, 0);
    }

    // ---- epilogue: out = x + acc ----
    #pragma unroll
    for (int Mt = 0; Mt < 4; ++Mt) {
        #pragma unroll
        for (int Nt = 0; Nt < 2; ++Nt) {
            int col = cb * 128 + wcol * 32 + Nt * 16 + l15;
            #pragma unroll
            for (int jj = 0; jj < 4; ++jj) {
                int row = rt * 128 + wr * 64 + Mt * 16 + g * 4 + jj;
                out[(size_t)row * 512 + col] = x[(size_t)row * 512 + col] + acc[Mt][Nt][jj];
            }
        }
    }
}

extern "C" void kernel_launch(void* const* d_in, const int* in_sizes, int n_in,
                              void* d_out, int out_size, void* d_ws, size_t ws_size,
                              hipStream_t stream) {
    (void)in_sizes; (void)n_in; (void)out_size; (void)ws_size;
    const float* x    = (const float*)d_in[0];
    const float* xe   = (const float*)d_in[1];
    const float* lns  = (const float*)d_in[2];
    const float* lnb  = (const float*)d_in[3];
    const float* Wq   = (const float*)d_in[4];
    const float* Wk   = (const float*)d_in[5];
    const float* Wv   = (const float*)d_in[6];
    float* out = (float*)d_out;
    char* ws = (char*)d_ws;

    size_t off_xx   = 0;                                    // bf16 [8192][512]   8 MB
    size_t off_qk   = off_xx   + (size_t)TT * CC * 2;       // bf16 [8192][128]   2 MB
    size_t off_wqkt = off_qk   + (size_t)TT * 128 * 2;      // bf16 [128][512]
    size_t off_wvt  = off_wqkt + (size_t)128 * 512 * 2;     // bf16 [512][512]
    size_t off_vt   = off_wvt  + (size_t)512 * 512 * 2;     // bf16 [512][8192]   8 MB
    size_t off_xeb  = off_vt   + (size_t)TT * CC * 2;       // bf16 [8192][512]   8 MB
    size_t off_kt   = off_xeb  + (size_t)TT * CC * 2;       // bf16 [64][8192]    1 MB
    size_t off_h    = off_kt   + (size_t)64 * TT * 2;       // f32  [64][512][64]  8.4 MB
    size_t off_as   = off_h    + (size_t)64 * 32768 * 4;    // f32  [8][32768]     1 MB
    size_t off_ptb  = off_as   + (size_t)8 * 32768 * 4;     // bf16 [64][512][64]  4.2 MB

    u16* xx   = (u16*)(ws + off_xx);
    u16* qk   = (u16*)(ws + off_qk);
    u16* wqkt = (u16*)(ws + off_wqkt);
    u16* wvt  = (u16*)(ws + off_wvt);
    u16* vt   = (u16*)(ws + off_vt);
    u16* xeb  = (u16*)(ws + off_xeb);
    u16* kt   = (u16*)(ws + off_kt);
    float* H  = (float*)(ws + off_h);
    float* As = (float*)(ws + off_as);
    u16* ptb  = (u16*)(ws + off_ptb);

    const size_t qkv_lds = 65536;   // 64 KB

    hipLaunchKernelGGL(lnw_kernel,      dim3(5376), dim3(256), 0, stream,
                       x, lns, lnb, Wq, Wk, Wv, xe, xx, wqkt, wvt, xeb);
    hipLaunchKernelGGL(qkv_gemm_kernel, dim3(320),  dim3(512), qkv_lds, stream,
                       xx, wqkt, xeb, wvt, qk, kt, vt);
    hipLaunchKernelGGL(gkv_kernel,      dim3(256),  dim3(512), 0, stream, vt, kt, H);
    hipLaunchKernelGGL(scanA_kernel,    dim3(1024), dim3(256), 0, stream, H, As);
    hipLaunchKernelGGL(scanB_kernel,    dim3(1024), dim3(256), 0, stream, H, As, ptb);
    hipLaunchKernelGGL(out_kernel,      dim3(256),  dim3(512), 0, stream, qk, ptb, vt, x, out);
}